// Round 5
// baseline (3003.630 us; speedup 1.0000x reference)
//
#include <hip/hip_runtime.h>
#include <math.h>

#define Nn 15000
#define Ee 30000
#define NB_E 118   // ceil(Ee/256)
#define EB 768     // k_edge3 blocks

// ---- workspace layout (float offsets) ----
// zero region (memset each call):
#define OFF_AGG   0          // [Nn*64]
#define OFF_DEG   960000     // [Nn]
#define ZERO_END  975000
// written-before-read region:
#define OFF_OUT   975008     // [Nn*64]
#define OFF_DINV  1935008    // [Nn]
#define OFF_AT    1950016    // [65*4096] transposed: At[p][o*64+i]
#define OFF_BT    2216256    // [65*4096]
#define OFF_BP    2482496    // [64]
#define OFF_U     2482560    // [65*64]
#define OFF_V     2486720    // [65*64]
#define OFF_MC    2490880    // [1] int
#define OFF_PE    2490884    // [Ee] int
#define OFF_BH    2520884    // [NB_E*65] int per-block hist
#define OFF_BC    2528554    // [NB_E*65] int per-block cursors
#define OFF_SS    2536224    // [Ee] int
#define OFF_SD    2566224    // [Ee] int
#define OFF_SA    2596224    // [Ee] float
#define OFF_SP    2626224    // [Ee] int
#define OFF_WAT   2656224    // [64*256] wAt[i*256+o]: o<64 root, o>=64 whh^T gates
#define OFF_WBT   2672608    // [64*192] wBt[i*192+g]: wih^T gates
#define OFF_GMA   2684896    // [256]
#define OFF_GSA   2685152    // [256]
#define OFF_GRA   2685408    // [256*64]
#define OFF_GMB   2701792    // [256]
#define OFF_GSB   2702048    // [256]
#define OFF_GRB   2702304    // [256*64]
#define OFF_HS    2718688    // [64]
#define OFF_CS    2718752    // [64]
#define WS_FLOATS 2718816

__device__ __forceinline__ float sigf(float x) { return 1.0f / (1.0f + expf(-x)); }
__device__ __forceinline__ float bcast(float v, int l) {
    return __int_as_float(__builtin_amdgcn_readlane(__float_as_int(v), l));
}

__global__ void k_lin0(const float* __restrict__ x, const float* __restrict__ w,
                       const float* __restrict__ b, float* __restrict__ out) {
    int idx = blockIdx.x * 256 + threadIdx.x;
    if (idx >= Nn * 64) return;
    int n = idx >> 6, o = idx & 63;
    float v = b[o] + x[n*3+0]*w[o*3+0] + x[n*3+1]*w[o*3+1] + x[n*3+2]*w[o*3+2];
    out[idx] = fmaxf(v, 0.0f);
}

// he[e,k] = relu(a*w1[k]+b1[k]) piecewise-linear in scalar a: <=64 breakpoints.
__global__ void k_patterns(const float* __restrict__ e1w, const float* __restrict__ e1b,
                           float* __restrict__ bp, float* __restrict__ u,
                           float* __restrict__ v, int* __restrict__ mc) {
    __shared__ float t[64]; __shared__ int valid[64]; __shared__ float sbp[65]; __shared__ int cnt;
    int k = threadIdx.x;
    float w1 = e1w[k], b1 = e1b[k];
    float tv = 0.f; int va = 0;
    if (w1 != 0.f) { tv = -b1 / w1; va = (tv > 0.f && tv < 1.f) ? 1 : 0; }
    t[k] = tv; valid[k] = va;
    __syncthreads();
    if (va) {
        int rank = 0;
        for (int kk = 0; kk < 64; ++kk)
            if (valid[kk] && (t[kk] < tv || (t[kk] == tv && kk < k))) rank++;
        sbp[rank] = tv;
    }
    if (k == 0) { int c = 0; for (int kk = 0; kk < 64; ++kk) c += valid[kk]; cnt = c; *mc = c; }
    __syncthreads();
    int m = cnt;
    if (k < m) bp[k] = sbp[k];
    for (int j = 0; j <= m; ++j) {
        float lo = (j == 0) ? 0.f : sbp[j-1];
        float hi = (j == m) ? 1.f : sbp[j];
        float c = 0.5f * (lo + hi);
        int msk = (c * w1 + b1) > 0.f;
        u[j*64 + k] = msk ? w1 : 0.f;
        v[j*64 + k] = msk ? b1 : 0.f;
    }
}

// transposed outputs: At[j][o*64+i] = sum_k u_j[k]*e2w[(i*64+o)*64+k]; Bt likewise + e2b
__global__ void k_AB(const float* __restrict__ e2w, const float* __restrict__ e2b,
                     const float* __restrict__ u, const float* __restrict__ v,
                     const int* __restrict__ mc, float* __restrict__ At, float* __restrict__ Bt) {
    int j = blockIdx.x;
    if (j > *mc) return;
    __shared__ float su[64], sv[64];
    if (threadIdx.x < 64) { su[threadIdx.x] = u[j*64+threadIdx.x]; sv[threadIdx.x] = v[j*64+threadIdx.x]; }
    __syncthreads();
    for (int q = threadIdx.x; q < 4096; q += 256) {
        int i = q >> 6, o = q & 63;
        const float* row = e2w + q*64;
        float a = 0.f, b = 0.f;
        #pragma unroll 8
        for (int k = 0; k < 64; ++k) { float w = row[k]; a = fmaf(su[k], w, a); b = fmaf(sv[k], w, b); }
        At[j*4096 + o*64 + i] = a;
        Bt[j*4096 + o*64 + i] = b + e2b[q];
    }
}

// per-block LDS histogram (no global hist atomics) + deg + classify
__global__ void k_eprep2(const int* __restrict__ ei, const float* __restrict__ ea,
                         const float* __restrict__ bp, const int* __restrict__ mc,
                         float* __restrict__ deg, int* __restrict__ pe, int* __restrict__ bh) {
    __shared__ int lh[65];
    int tid = threadIdx.x;
    if (tid < 65) lh[tid] = 0;
    __syncthreads();
    int e = blockIdx.x * 256 + tid;
    if (e < Ee) {
        atomicAdd(&deg[ei[Ee + e]], 1.0f);
        float a = ea[e];
        int m = *mc, p = 0;
        for (int j = 0; j < m; ++j) p += (bp[j] <= a) ? 1 : 0;
        pe[e] = p;
        atomicAdd(&lh[p], 1);
    }
    __syncthreads();
    if (tid < 65) bh[blockIdx.x*65 + tid] = lh[tid];
}

// blocks 0..58: dinv; block 59: two-level scan -> per-block per-bin cursors
__global__ void k_scan2(const float* __restrict__ deg, float* __restrict__ dinv,
                        const int* __restrict__ bh, int* __restrict__ bc) {
    int tid = threadIdx.x;
    if (blockIdx.x < 59) {
        int n = blockIdx.x * 256 + tid;
        if (n < Nn) dinv[n] = 1.0f / fmaxf(deg[n], 1.0f);
        return;
    }
    __shared__ int stot[65]; __shared__ int sbase[65];
    if (tid < 65) {
        int t = 0;
        for (int b = 0; b < NB_E; ++b) t += bh[b*65 + tid];
        stot[tid] = t;
    }
    __syncthreads();
    if (tid == 0) {
        int run = 0;
        for (int j = 0; j < 65; ++j) { sbase[j] = run; run += stot[j]; }
    }
    __syncthreads();
    if (tid < 65) {
        int run = sbase[tid];
        for (int b = 0; b < NB_E; ++b) { bc[b*65 + tid] = run; run += bh[b*65 + tid]; }
    }
}

// scatter using per-block LDS cursors (LDS atomics only)
__global__ void k_scatter2(const int* __restrict__ ei, const float* __restrict__ ea,
                           const int* __restrict__ pe, const int* __restrict__ bc,
                           int* __restrict__ sS, int* __restrict__ sD,
                           float* __restrict__ sA, int* __restrict__ sP) {
    __shared__ int cur[65];
    int tid = threadIdx.x;
    if (tid < 65) cur[tid] = bc[blockIdx.x*65 + tid];
    __syncthreads();
    int e = blockIdx.x * 256 + tid;
    if (e >= Ee) return;
    int p = pe[e];
    int pos = atomicAdd(&cur[p], 1);
    sS[pos] = ei[e]; sD[pos] = ei[Ee + e]; sA[pos] = ea[e]; sP[pos] = p;
}

// transposed weight tables: wAt[i][0..63]=root_w[i][o]; wAt[i][64+g]=whh[g][i]; wBt[i][g]=wih[g][i]
__global__ void k_wt(const float* __restrict__ rootw, const float* __restrict__ whh,
                     const float* __restrict__ wih, float* __restrict__ wAt, float* __restrict__ wBt) {
    int idx = blockIdx.x * 256 + threadIdx.x;
    if (idx < 16384) {
        int i = idx >> 8, o = idx & 255;
        wAt[idx] = (o < 64) ? rootw[i*64 + o] : whh[(o-64)*64 + i];
    } else if (idx < 16384 + 12288) {
        int j = idx - 16384;
        int i = j / 192, g = j % 192;
        wBt[j] = wih[g*64 + i];
    }
}

// pattern-sorted edges, VGPR-cached pattern columns (float4 reload from transposed At/Bt)
__global__ __launch_bounds__(256) void k_edge3(
        const int* __restrict__ sS, const int* __restrict__ sD,
        const float* __restrict__ sA, const int* __restrict__ sP,
        const float* __restrict__ out, const float* __restrict__ At,
        const float* __restrict__ Bt, const float* __restrict__ dinv,
        float* __restrict__ agg) {
    int tid = threadIdx.x, lane = tid & 63;
    int wid = (blockIdx.x * 256 + tid) >> 6;       // 0..EB*4-1
    const int NW = EB * 4;
    const int CH = (Ee + NW - 1) / NW;
    int e0 = wid * CH;
    int e1 = e0 + CH; if (e1 > Ee) e1 = Ee;
    float Ar[64], Br[64];
    int curp = -1;
    for (int e = e0; e < e1; ++e) {
        int p = sP[e];
        if (p != curp) {
            curp = p;
            const float4* Ap4 = (const float4*)(At + p*4096 + lane*64);
            const float4* Bp4 = (const float4*)(Bt + p*4096 + lane*64);
            #pragma unroll
            for (int q = 0; q < 16; ++q) {
                float4 av = Ap4[q], bv = Bp4[q];
                Ar[q*4+0]=av.x; Ar[q*4+1]=av.y; Ar[q*4+2]=av.z; Ar[q*4+3]=av.w;
                Br[q*4+0]=bv.x; Br[q*4+1]=bv.y; Br[q*4+2]=bv.z; Br[q*4+3]=bv.w;
            }
        }
        int src = sS[e], dst = sD[e];
        float a = sA[e];
        float hv = out[src*64 + lane];
        float acc0 = 0.f, acc1 = 0.f;
        #pragma unroll
        for (int i = 0; i < 64; i += 2) {
            float h0 = bcast(hv, i);
            float h1 = bcast(hv, i+1);
            acc0 = fmaf(h0, fmaf(a, Ar[i],   Br[i]),   acc0);
            acc1 = fmaf(h1, fmaf(a, Ar[i+1], Br[i+1]), acc1);
        }
        float acc = (acc0 + acc1) * dinv[dst];
        atomicAdd(&agg[dst*64 + lane], acc);
    }
}

// K-loop body: acc[0..7] += v[i] * w[i*STRIDE + j] for 4 i per float4
template<int STRIDE>
__device__ __forceinline__ void mv8(const float4* __restrict__ v4,
                                    const float* __restrict__ w, float* acc) {
    #pragma unroll
    for (int i4 = 0; i4 < 16; ++i4) {
        float4 hv = v4[i4];
        const float* w0 = w + (i4*4)*STRIDE;
        #pragma unroll
        for (int j = 0; j < 8; ++j)
            acc[j] = fmaf(hv.x, w0[j],
                     fmaf(hv.y, w0[STRIDE+j],
                     fmaf(hv.z, w0[2*STRIDE+j],
                     fmaf(hv.w, w0[3*STRIDE+j], acc[j]))));
    }
}

// fused NNConv-root + full GRU. lane = node (64-node tile), 8 waves x 8 output
// cols. h/m node-major in LDS (stride 68) -> ds_read_b128 K-loop; weights
// wave-uniform -> s_load (scalar pipe). Peak live accumulators = 32 (no spill).
__global__ __launch_bounds__(512) void k_gru4(
        float* __restrict__ out, float* __restrict__ agg,
        const float* __restrict__ wAt, const float* __restrict__ wBt,
        const float* __restrict__ convb, const float* __restrict__ gbih,
        const float* __restrict__ gbhh) {
    __shared__ __align__(16) float hN[64*68];   // hN[n*68+i] = h[n][i]
    __shared__ __align__(16) float mN[64*68];
    __shared__ float xT[64*65];                 // aggT staging, then outT staging
    int tid = threadIdx.x, lane = tid & 63;
    int ob = __builtin_amdgcn_readfirstlane((tid >> 6) * 8);   // wave's 8-col base
    int n0 = blockIdx.x * 64;
    const int base4 = n0 * 16;                  // float4 index into out/agg

    // stage: h node-major (float4), agg transposed into xT; zero agg
    float4* out4 = (float4*)out;
    float4* agg4 = (float4*)agg;
    #pragma unroll
    for (int p = 0; p < 2; ++p) {
        int idx = p*512 + tid;                  // 0..1023
        int n = idx >> 4, i4 = idx & 15;
        float4 hv = make_float4(0.f,0.f,0.f,0.f), av = make_float4(0.f,0.f,0.f,0.f);
        if (base4 + idx < Nn*16) {
            hv = out4[base4 + idx];
            av = agg4[base4 + idx];
            agg4[base4 + idx] = make_float4(0.f,0.f,0.f,0.f);
        }
        *(float4*)(hN + n*68 + i4*4) = hv;
        xT[(i4*4+0)*65 + n] = av.x;
        xT[(i4*4+1)*65 + n] = av.y;
        xT[(i4*4+2)*65 + n] = av.z;
        xT[(i4*4+3)*65 + n] = av.w;
    }
    __syncthreads();

    const float4* h4 = (const float4*)hN + lane*17;
    const float4* m4 = (const float4*)mN + lane*17;
    const float* wA = wAt + ob;
    const float* wB = wBt + ob;

    // P1: root matvec -> m = relu(root + agg + convb) -> mN
    float a0[8];
    #pragma unroll
    for (int j = 0; j < 8; ++j) a0[j] = 0.f;
    mv8<256>(h4, wA, a0);
    #pragma unroll
    for (int j = 0; j < 8; ++j)
        mN[lane*68 + ob + j] = fmaxf(a0[j] + xT[(ob+j)*65 + lane] + convb[ob+j], 0.f);
    __syncthreads();   // mN complete; xT free

    // P2: r gate (gi_r + gh_r accumulated together)
    #pragma unroll
    for (int j = 0; j < 8; ++j) a0[j] = gbih[ob+j] + gbhh[ob+j];
    mv8<256>(h4, wA + 64, a0);
    mv8<192>(m4, wB, a0);
    float r[8];
    #pragma unroll
    for (int j = 0; j < 8; ++j) r[j] = sigf(a0[j]);

    // P3: z gate
    #pragma unroll
    for (int j = 0; j < 8; ++j) a0[j] = gbih[64+ob+j] + gbhh[64+ob+j];
    mv8<256>(h4, wA + 128, a0);
    mv8<192>(m4, wB + 64, a0);
    float z[8];
    #pragma unroll
    for (int j = 0; j < 8; ++j) z[j] = sigf(a0[j]);

    // P4: n gate (gh_n and gi_n separate; r scales gh_n only)
    float a1[8];
    #pragma unroll
    for (int j = 0; j < 8; ++j) { a0[j] = gbhh[128+ob+j]; a1[j] = gbih[128+ob+j]; }
    mv8<256>(h4, wA + 192, a0);
    mv8<192>(m4, wB + 128, a1);
    #pragma unroll
    for (int j = 0; j < 8; ++j) {
        float nn = tanhf(fmaf(r[j], a0[j], a1[j]));
        float h  = hN[lane*68 + ob + j];
        xT[(ob+j)*65 + lane] = (1.f - z[j])*nn + z[j]*h;
    }
    __syncthreads();

    // coalesced out write from xT
    #pragma unroll
    for (int p = 0; p < 2; ++p) {
        int idx = p*512 + tid;
        int n = idx >> 4, i4 = idx & 15;
        if (base4 + idx < Nn*16) {
            float4 ov;
            ov.x = xT[(i4*4+0)*65 + n];
            ov.y = xT[(i4*4+1)*65 + n];
            ov.z = xT[(i4*4+2)*65 + n];
            ov.w = xT[(i4*4+3)*65 + n];
            out4[base4 + idx] = ov;
        }
    }
}

// one launch per Set2Set iteration: every block redundantly finalizes prev partials
// + runs the tiny LSTM (identical f32 math in all blocks), then computes its
// online-softmax partials with the fresh hs. Double-buffered partials (rd/wr).
__global__ __launch_bounds__(256) void k_s2s(
        const float* __restrict__ wih, const float* __restrict__ whh,
        const float* __restrict__ bih, const float* __restrict__ bhh,
        float* __restrict__ hs, float* __restrict__ cs,
        const float* __restrict__ out,
        const float* __restrict__ gmax_rd, const float* __restrict__ gsum_rd,
        const float* __restrict__ gr_rd,
        float* __restrict__ gmax_wr, float* __restrict__ gsum_wr,
        float* __restrict__ gr_wr, int it) {
    __shared__ float red[256], shs[64], scs[64], srv[64], sg[256];
    __shared__ float sm_m[4], sm_z[4], sm_r[4][64];
    int tid = threadIdx.x, lane = tid & 63, w = tid >> 6;

    if (it == 0) {
        if (tid < 64) { shs[tid] = 0.f; scs[tid] = 0.f; srv[tid] = 0.f; }
    } else {
        float gm = gmax_rd[tid];
        red[tid] = gm; __syncthreads();
        for (int s = 128; s > 0; s >>= 1) { if (tid < s) red[tid] = fmaxf(red[tid], red[tid+s]); __syncthreads(); }
        float M = red[0]; __syncthreads();
        red[tid] = gsum_rd[tid] * expf(gm - M); __syncthreads();
        for (int s = 128; s > 0; s >>= 1) { if (tid < s) red[tid] += red[tid+s]; __syncthreads(); }
        float Z = red[0]; __syncthreads();
        float racc = 0.f;
        for (int b = w; b < 256; b += 4) racc = fmaf(gr_rd[b*64 + lane], expf(gmax_rd[b] - M), racc);
        red[tid] = racc; __syncthreads();
        if (w == 0) srv[lane] = (red[lane] + red[64+lane] + red[128+lane] + red[192+lane]) / Z;
        if (tid < 64) { shs[tid] = hs[tid]; scs[tid] = cs[tid]; }
    }
    __syncthreads();

    // LSTM: g[tid] over 256 gates
    {
        const float* wi = wih + tid*128;
        const float* wh = whh + tid*64;
        float g = bih[tid] + bhh[tid];
        #pragma unroll 8
        for (int i = 0; i < 64; ++i) g += shs[i]*(wi[i] + wh[i]) + srv[i]*wi[64+i];
        sg[tid] = g;
    }
    __syncthreads();
    if (tid < 64) {
        float ii = sigf(sg[tid]), ff = sigf(sg[64+tid]);
        float gg = tanhf(sg[128+tid]), oo = sigf(sg[192+tid]);
        float c2 = ff*scs[tid] + ii*gg;
        float hn = oo*tanhf(c2);
        shs[tid] = hn;
        if (blockIdx.x == 0) { hs[tid] = hn; cs[tid] = c2; }
    }
    __syncthreads();

    // online-softmax partials with fresh hs
    float hsv = shs[lane];
    float m = -3.4e38f, Z2 = 0.f, racc2 = 0.f;
    for (int n = blockIdx.x*4 + w; n < Nn; n += 1024) {
        float ov = out[n*64 + lane];
        float p = ov * hsv;
        #pragma unroll
        for (int off = 32; off > 0; off >>= 1) p += __shfl_xor(p, off, 64);
        float mn = fmaxf(m, p);
        float sc = expf(m - mn);
        float t  = expf(p - mn);
        Z2 = fmaf(Z2, sc, t);
        racc2 = fmaf(racc2, sc, t*ov);
        m = mn;
    }
    if (lane == 0) { sm_m[w] = m; sm_z[w] = Z2; }
    sm_r[w][lane] = racc2;
    __syncthreads();
    if (w == 0) {
        float M = fmaxf(fmaxf(sm_m[0], sm_m[1]), fmaxf(sm_m[2], sm_m[3]));
        float Zb = 0.f, rb = 0.f;
        #pragma unroll
        for (int j = 0; j < 4; ++j) {
            float e = expf(sm_m[j] - M);
            Zb = fmaf(sm_z[j], e, Zb);
            rb = fmaf(sm_r[j][lane], e, rb);
        }
        gr_wr[blockIdx.x*64 + lane] = rb;
        if (lane == 0) { gmax_wr[blockIdx.x] = M; gsum_wr[blockIdx.x] = Zb; }
    }
}

// final: finalize rv, mem-LSTM (h=c=0), lin1, lin3 -> dout = [v, hx(64), cx(64)]
__global__ __launch_bounds__(256) void k_final2(const float* __restrict__ mwih,
        const float* __restrict__ mbih, const float* __restrict__ mbhh,
        const float* __restrict__ hs,
        const float* __restrict__ gmax, const float* __restrict__ gsum,
        const float* __restrict__ gr,
        const float* __restrict__ l1w, const float* __restrict__ l1b,
        const float* __restrict__ l3w, const float* __restrict__ l3b,
        float* __restrict__ dout) {
    __shared__ float red[256], shs[64], srv[64], sg[256], shx[64], so[64];
    int tid = threadIdx.x, lane = tid & 63, w = tid >> 6;
    {
        float gm = gmax[tid];
        red[tid] = gm; __syncthreads();
        for (int s = 128; s > 0; s >>= 1) { if (tid < s) red[tid] = fmaxf(red[tid], red[tid+s]); __syncthreads(); }
        float M = red[0]; __syncthreads();
        red[tid] = gsum[tid] * expf(gm - M); __syncthreads();
        for (int s = 128; s > 0; s >>= 1) { if (tid < s) red[tid] += red[tid+s]; __syncthreads(); }
        float Z = red[0]; __syncthreads();
        float racc = 0.f;
        for (int b = w; b < 256; b += 4) racc = fmaf(gr[b*64 + lane], expf(gmax[b] - M), racc);
        red[tid] = racc; __syncthreads();
        if (w == 0) srv[lane] = (red[lane] + red[64+lane] + red[128+lane] + red[192+lane]) / Z;
        if (tid < 64) shs[tid] = hs[tid];
    }
    __syncthreads();
    const float* wi = mwih + tid*128;
    float g = mbih[tid] + mbhh[tid];
    #pragma unroll 8
    for (int i = 0; i < 64; ++i) g += shs[i]*wi[i] + srv[i]*wi[64+i];
    sg[tid] = g; __syncthreads();
    if (tid < 64) {
        float ii = sigf(sg[tid]);
        float gg = tanhf(sg[128+tid]);
        float oo = sigf(sg[192+tid]);
        float c2 = ii * gg;
        float hx = oo * tanhf(c2);
        shx[tid] = hx;
        dout[1 + tid] = hx;
        dout[65 + tid] = c2;
    }
    __syncthreads();
    if (tid < 64) {
        float a = l1b[tid];
        const float* wr = l1w + tid*64;
        #pragma unroll 8
        for (int i = 0; i < 64; ++i) a = fmaf(shx[i], wr[i], a);
        so[tid] = fmaxf(a, 0.f);
    }
    __syncthreads();
    if (tid == 0) {
        float v = l3b[0];
        for (int i = 0; i < 64; ++i) v = fmaf(so[i], l3w[i], v);
        dout[0] = v;
    }
}

extern "C" void kernel_launch(void* const* d_in, const int* in_sizes, int n_in,
                              void* d_out, int out_size, void* d_ws, size_t ws_size,
                              hipStream_t stream) {
    const float* x    = (const float*)d_in[0];
    const int*   ei   = (const int*)  d_in[1];
    const float* ea   = (const float*)d_in[2];
    const float* l0w  = (const float*)d_in[3];
    const float* l0b  = (const float*)d_in[4];
    const float* e1w  = (const float*)d_in[5];
    const float* e1b  = (const float*)d_in[6];
    const float* e2w  = (const float*)d_in[7];
    const float* e2b  = (const float*)d_in[8];
    const float* rootw= (const float*)d_in[9];
    const float* convb= (const float*)d_in[10];
    const float* gwih = (const float*)d_in[11];
    const float* gwhh = (const float*)d_in[12];
    const float* gbih = (const float*)d_in[13];
    const float* gbhh = (const float*)d_in[14];
    const float* swih = (const float*)d_in[15];
    const float* swhh = (const float*)d_in[16];
    const float* sbih = (const float*)d_in[17];
    const float* sbhh = (const float*)d_in[18];
    const float* mwih = (const float*)d_in[19];
    const float* mbih = (const float*)d_in[21];
    const float* mbhh = (const float*)d_in[22];
    const float* l1w  = (const float*)d_in[23];
    const float* l1b  = (const float*)d_in[24];
    const float* l3w  = (const float*)d_in[25];
    const float* l3b  = (const float*)d_in[26];

    float* ws   = (float*)d_ws;
    float* dout = (float*)d_out;
    if (ws_size < (size_t)WS_FLOATS * sizeof(float)) return;

    float* agg  = ws + OFF_AGG;
    float* deg  = ws + OFF_DEG;
    float* out  = ws + OFF_OUT;
    float* dinv = ws + OFF_DINV;
    float* At   = ws + OFF_AT;
    float* Bt   = ws + OFF_BT;
    float* bp   = ws + OFF_BP;
    float* ubuf = ws + OFF_U;
    float* vbuf = ws + OFF_V;
    int*   mc   = (int*)(ws + OFF_MC);
    int*   pe   = (int*)(ws + OFF_PE);
    int*   bh   = (int*)(ws + OFF_BH);
    int*   bc   = (int*)(ws + OFF_BC);
    int*   sS   = (int*)(ws + OFF_SS);
    int*   sD   = (int*)(ws + OFF_SD);
    float* sA   = ws + OFF_SA;
    int*   sP   = (int*)(ws + OFF_SP);
    float* wAt  = ws + OFF_WAT;
    float* wBt  = ws + OFF_WBT;
    float* gmA  = ws + OFF_GMA;
    float* gsA  = ws + OFF_GSA;
    float* grA  = ws + OFF_GRA;
    float* gmB  = ws + OFF_GMB;
    float* gsB  = ws + OFF_GSB;
    float* grB  = ws + OFF_GRB;
    float* hs   = ws + OFF_HS;
    float* cs   = ws + OFF_CS;

    hipMemsetAsync(d_ws, 0, (size_t)ZERO_END * sizeof(float), stream);

    k_lin0    <<<(Nn*64 + 255)/256, 256, 0, stream>>>(x, l0w, l0b, out);
    k_patterns<<<1, 64, 0, stream>>>(e1w, e1b, bp, ubuf, vbuf, mc);
    k_AB      <<<65, 256, 0, stream>>>(e2w, e2b, ubuf, vbuf, mc, At, Bt);
    k_eprep2  <<<NB_E, 256, 0, stream>>>(ei, ea, bp, mc, deg, pe, bh);
    k_scan2   <<<60, 256, 0, stream>>>(deg, dinv, bh, bc);
    k_scatter2<<<NB_E, 256, 0, stream>>>(ei, ea, pe, bc, sS, sD, sA, sP);
    k_wt      <<<(16384 + 12288 + 255)/256, 256, 0, stream>>>(rootw, gwhh, gwih, wAt, wBt);

    for (int s = 0; s < 6; ++s) {
        k_edge3<<<EB, 256, 0, stream>>>(sS, sD, sA, sP, out, At, Bt, dinv, agg);
        k_gru4 <<<(Nn + 63)/64, 512, 0, stream>>>(out, agg, wAt, wBt, convb, gbih, gbhh);
    }

    for (int it = 0; it < 6; ++it) {
        float* gm_rd = (it & 1) ? gmA : gmB;   // unused at it=0
        float* gs_rd = (it & 1) ? gsA : gsB;
        float* gr_rd = (it & 1) ? grA : grB;
        float* gm_wr = (it & 1) ? gmB : gmA;
        float* gs_wr = (it & 1) ? gsB : gsA;
        float* gr_wr = (it & 1) ? grB : grA;
        k_s2s<<<256, 256, 0, stream>>>(swih, swhh, sbih, sbhh, hs, cs, out,
                                       gm_rd, gs_rd, gr_rd, gm_wr, gs_wr, gr_wr, it);
    }

    // it=5 wrote the B buffers
    k_final2<<<1, 256, 0, stream>>>(mwih, mbih, mbhh, hs, gmB, gsB, grB,
                                    l1w, l1b, l3w, l3b, dout);
}

// Round 6
// 778.101 us; speedup vs baseline: 3.8602x; 3.8602x over previous
//
#include <hip/hip_runtime.h>
#include <math.h>

#define Nn 15000
#define Ee 30000
#define NB_E 118   // ceil(Ee/256)
#define EB 768     // k_edge3 blocks

// ---- workspace layout (float offsets) ----
// zero region (memset each call):
#define OFF_AGG   0          // [Nn*64]
#define OFF_DEG   960000     // [Nn]
#define ZERO_END  975000
// written-before-read region:
#define OFF_OUT   975008     // [Nn*64]
#define OFF_DINV  1935008    // [Nn]
#define OFF_AT    1950016    // [65*4096] transposed: At[p][o*64+i]
#define OFF_BT    2216256    // [65*4096]
#define OFF_BP    2482496    // [64]
#define OFF_U     2482560    // [65*64]
#define OFF_V     2486720    // [65*64]
#define OFF_MC    2490880    // [1] int
#define OFF_PE    2490884    // [Ee] int
#define OFF_BH    2520884    // [NB_E*65] int per-block hist
#define OFF_BC    2528554    // [NB_E*65] int per-block cursors
#define OFF_SS    2536224    // [Ee] int
#define OFF_SD    2566224    // [Ee] int
#define OFF_SA    2596224    // [Ee] float
#define OFF_SP    2626224    // [Ee] int
#define OFF_WAT   2656224    // [64*256] wAt[i*256+o]: o<64 root, o>=64 whh^T gates
#define OFF_WBT   2672608    // [64*192] wBt[i*192+g]: wih^T gates
#define OFF_GMA   2684896    // [256]
#define OFF_GSA   2685152    // [256]
#define OFF_GRA   2685408    // [256*64]
#define OFF_GMB   2701792    // [256]
#define OFF_GSB   2702048    // [256]
#define OFF_GRB   2702304    // [256*64]
#define OFF_HS    2718688    // [64]
#define OFF_CS    2718752    // [64]
#define WS_FLOATS 2718816

__device__ __forceinline__ float sigf(float x) { return 1.0f / (1.0f + expf(-x)); }
__device__ __forceinline__ float bcast(float v, int l) {
    return __int_as_float(__builtin_amdgcn_readlane(__float_as_int(v), l));
}

__global__ void k_lin0(const float* __restrict__ x, const float* __restrict__ w,
                       const float* __restrict__ b, float* __restrict__ out) {
    int idx = blockIdx.x * 256 + threadIdx.x;
    if (idx >= Nn * 64) return;
    int n = idx >> 6, o = idx & 63;
    float v = b[o] + x[n*3+0]*w[o*3+0] + x[n*3+1]*w[o*3+1] + x[n*3+2]*w[o*3+2];
    out[idx] = fmaxf(v, 0.0f);
}

// he[e,k] = relu(a*w1[k]+b1[k]) piecewise-linear in scalar a: <=64 breakpoints.
__global__ void k_patterns(const float* __restrict__ e1w, const float* __restrict__ e1b,
                           float* __restrict__ bp, float* __restrict__ u,
                           float* __restrict__ v, int* __restrict__ mc) {
    __shared__ float t[64]; __shared__ int valid[64]; __shared__ float sbp[65]; __shared__ int cnt;
    int k = threadIdx.x;
    float w1 = e1w[k], b1 = e1b[k];
    float tv = 0.f; int va = 0;
    if (w1 != 0.f) { tv = -b1 / w1; va = (tv > 0.f && tv < 1.f) ? 1 : 0; }
    t[k] = tv; valid[k] = va;
    __syncthreads();
    if (va) {
        int rank = 0;
        for (int kk = 0; kk < 64; ++kk)
            if (valid[kk] && (t[kk] < tv || (t[kk] == tv && kk < k))) rank++;
        sbp[rank] = tv;
    }
    if (k == 0) { int c = 0; for (int kk = 0; kk < 64; ++kk) c += valid[kk]; cnt = c; *mc = c; }
    __syncthreads();
    int m = cnt;
    if (k < m) bp[k] = sbp[k];
    for (int j = 0; j <= m; ++j) {
        float lo = (j == 0) ? 0.f : sbp[j-1];
        float hi = (j == m) ? 1.f : sbp[j];
        float c = 0.5f * (lo + hi);
        int msk = (c * w1 + b1) > 0.f;
        u[j*64 + k] = msk ? w1 : 0.f;
        v[j*64 + k] = msk ? b1 : 0.f;
    }
}

// transposed outputs: At[j][o*64+i] = sum_k u_j[k]*e2w[(i*64+o)*64+k]; Bt likewise + e2b
__global__ void k_AB(const float* __restrict__ e2w, const float* __restrict__ e2b,
                     const float* __restrict__ u, const float* __restrict__ v,
                     const int* __restrict__ mc, float* __restrict__ At, float* __restrict__ Bt) {
    int j = blockIdx.x;
    if (j > *mc) return;
    __shared__ float su[64], sv[64];
    if (threadIdx.x < 64) { su[threadIdx.x] = u[j*64+threadIdx.x]; sv[threadIdx.x] = v[j*64+threadIdx.x]; }
    __syncthreads();
    for (int q = threadIdx.x; q < 4096; q += 256) {
        int i = q >> 6, o = q & 63;
        const float* row = e2w + q*64;
        float a = 0.f, b = 0.f;
        #pragma unroll 8
        for (int k = 0; k < 64; ++k) { float w = row[k]; a = fmaf(su[k], w, a); b = fmaf(sv[k], w, b); }
        At[j*4096 + o*64 + i] = a;
        Bt[j*4096 + o*64 + i] = b + e2b[q];
    }
}

// per-block LDS histogram (no global hist atomics) + deg + classify
__global__ void k_eprep2(const int* __restrict__ ei, const float* __restrict__ ea,
                         const float* __restrict__ bp, const int* __restrict__ mc,
                         float* __restrict__ deg, int* __restrict__ pe, int* __restrict__ bh) {
    __shared__ int lh[65];
    int tid = threadIdx.x;
    if (tid < 65) lh[tid] = 0;
    __syncthreads();
    int e = blockIdx.x * 256 + tid;
    if (e < Ee) {
        atomicAdd(&deg[ei[Ee + e]], 1.0f);
        float a = ea[e];
        int m = *mc, p = 0;
        for (int j = 0; j < m; ++j) p += (bp[j] <= a) ? 1 : 0;
        pe[e] = p;
        atomicAdd(&lh[p], 1);
    }
    __syncthreads();
    if (tid < 65) bh[blockIdx.x*65 + tid] = lh[tid];
}

// blocks 0..58: dinv; block 59: two-level scan -> per-block per-bin cursors
__global__ void k_scan2(const float* __restrict__ deg, float* __restrict__ dinv,
                        const int* __restrict__ bh, int* __restrict__ bc) {
    int tid = threadIdx.x;
    if (blockIdx.x < 59) {
        int n = blockIdx.x * 256 + tid;
        if (n < Nn) dinv[n] = 1.0f / fmaxf(deg[n], 1.0f);
        return;
    }
    __shared__ int stot[65]; __shared__ int sbase[65];
    if (tid < 65) {
        int t = 0;
        for (int b = 0; b < NB_E; ++b) t += bh[b*65 + tid];
        stot[tid] = t;
    }
    __syncthreads();
    if (tid == 0) {
        int run = 0;
        for (int j = 0; j < 65; ++j) { sbase[j] = run; run += stot[j]; }
    }
    __syncthreads();
    if (tid < 65) {
        int run = sbase[tid];
        for (int b = 0; b < NB_E; ++b) { bc[b*65 + tid] = run; run += bh[b*65 + tid]; }
    }
}

// scatter using per-block LDS cursors (LDS atomics only)
__global__ void k_scatter2(const int* __restrict__ ei, const float* __restrict__ ea,
                           const int* __restrict__ pe, const int* __restrict__ bc,
                           int* __restrict__ sS, int* __restrict__ sD,
                           float* __restrict__ sA, int* __restrict__ sP) {
    __shared__ int cur[65];
    int tid = threadIdx.x;
    if (tid < 65) cur[tid] = bc[blockIdx.x*65 + tid];
    __syncthreads();
    int e = blockIdx.x * 256 + tid;
    if (e >= Ee) return;
    int p = pe[e];
    int pos = atomicAdd(&cur[p], 1);
    sS[pos] = ei[e]; sD[pos] = ei[Ee + e]; sA[pos] = ea[e]; sP[pos] = p;
}

// transposed weight tables: wAt[i][0..63]=root_w[i][o]; wAt[i][64+g]=whh[g][i]; wBt[i][g]=wih[g][i]
__global__ void k_wt(const float* __restrict__ rootw, const float* __restrict__ whh,
                     const float* __restrict__ wih, float* __restrict__ wAt, float* __restrict__ wBt) {
    int idx = blockIdx.x * 256 + threadIdx.x;
    if (idx < 16384) {
        int i = idx >> 8, o = idx & 255;
        wAt[idx] = (o < 64) ? rootw[i*64 + o] : whh[(o-64)*64 + i];
    } else if (idx < 16384 + 12288) {
        int j = idx - 16384;
        int i = j / 192, g = j % 192;
        wBt[j] = wih[g*64 + i];
    }
}

// pattern-sorted edges, VGPR-cached pattern columns (float4 reload from transposed At/Bt)
__global__ __launch_bounds__(256) void k_edge3(
        const int* __restrict__ sS, const int* __restrict__ sD,
        const float* __restrict__ sA, const int* __restrict__ sP,
        const float* __restrict__ out, const float* __restrict__ At,
        const float* __restrict__ Bt, const float* __restrict__ dinv,
        float* __restrict__ agg) {
    int tid = threadIdx.x, lane = tid & 63;
    int wid = (blockIdx.x * 256 + tid) >> 6;       // 0..EB*4-1
    const int NW = EB * 4;
    const int CH = (Ee + NW - 1) / NW;
    int e0 = wid * CH;
    int e1 = e0 + CH; if (e1 > Ee) e1 = Ee;
    float Ar[64], Br[64];
    int curp = -1;
    for (int e = e0; e < e1; ++e) {
        int p = sP[e];
        if (p != curp) {
            curp = p;
            const float4* Ap4 = (const float4*)(At + p*4096 + lane*64);
            const float4* Bp4 = (const float4*)(Bt + p*4096 + lane*64);
            #pragma unroll
            for (int q = 0; q < 16; ++q) {
                float4 av = Ap4[q], bv = Bp4[q];
                Ar[q*4+0]=av.x; Ar[q*4+1]=av.y; Ar[q*4+2]=av.z; Ar[q*4+3]=av.w;
                Br[q*4+0]=bv.x; Br[q*4+1]=bv.y; Br[q*4+2]=bv.z; Br[q*4+3]=bv.w;
            }
        }
        int src = sS[e], dst = sD[e];
        float a = sA[e];
        float hv = out[src*64 + lane];
        float acc0 = 0.f, acc1 = 0.f;
        #pragma unroll
        for (int i = 0; i < 64; i += 2) {
            float h0 = bcast(hv, i);
            float h1 = bcast(hv, i+1);
            acc0 = fmaf(h0, fmaf(a, Ar[i],   Br[i]),   acc0);
            acc1 = fmaf(h1, fmaf(a, Ar[i+1], Br[i+1]), acc1);
        }
        float acc = (acc0 + acc1) * dinv[dst];
        atomicAdd(&agg[dst*64 + lane], acc);
    }
}

// h-matvec: acc[0..7] += h[i] * w[i*256 + j], h entirely in registers (hreg)
__device__ __forceinline__ void mv8h(const float4* __restrict__ hreg,
                                     const float* __restrict__ w, float* acc) {
    #pragma unroll
    for (int i4 = 0; i4 < 16; ++i4) {
        float4 hv = hreg[i4];
        const float* w0 = w + (i4*4)*256;
        #pragma unroll
        for (int j = 0; j < 8; ++j)
            acc[j] = fmaf(hv.x, w0[j],
                     fmaf(hv.y, w0[256+j],
                     fmaf(hv.z, w0[512+j],
                     fmaf(hv.w, w0[768+j], acc[j]))));
    }
}

// m-matvec: acc[0..7] += m[i] * w[i*192 + j], m row from swizzled LDS
__device__ __forceinline__ void mv8m(const float* __restrict__ row, int sw,
                                     const float* __restrict__ w, float* acc) {
    #pragma unroll 4
    for (int i4 = 0; i4 < 16; ++i4) {
        float4 hv = *(const float4*)(row + ((i4 ^ sw) << 2));
        const float* w0 = w + (i4*4)*192;
        #pragma unroll
        for (int j = 0; j < 8; ++j)
            acc[j] = fmaf(hv.x, w0[j],
                     fmaf(hv.y, w0[192+j],
                     fmaf(hv.z, w0[384+j],
                     fmaf(hv.w, w0[576+j], acc[j]))));
    }
}

// fused NNConv-root + full GRU. lane = node (64-node tile), 8 waves x 8 cols.
// h row in 64 VGPRs; weights wave-uniform -> s_load (scalar pipe); m in
// XOR-swizzled LDS (bank = 4(n+slot) mod 32: conflict-optimal b128).
// __launch_bounds__(512,2): VGPR cap 256 -> no spill; 2 waves/SIMD.
__global__ __launch_bounds__(512, 2) void k_gru5(
        float* __restrict__ out, float* __restrict__ agg,
        const float* __restrict__ wAt, const float* __restrict__ wBt,
        const float* __restrict__ convb, const float* __restrict__ gbih,
        const float* __restrict__ gbhh) {
    __shared__ __align__(16) float hN[64*68];   // row n at n*68, float4 slot q at (q^((n&7)<<1))*4
    __shared__ __align__(16) float mN[64*68];   // staged agg, then m
    int tid = threadIdx.x, lane = tid & 63;
    int sw = (lane & 7) << 1;
    int ob = __builtin_amdgcn_readfirstlane((tid >> 6) * 8);   // wave's 8-col base
    int n0 = blockIdx.x * 64;
    const int base4 = n0 * 16;
    float4* out4 = (float4*)out;
    float4* agg4 = (float4*)agg;

    // stage h and agg node-major swizzled; zero agg (coalesced global)
    #pragma unroll
    for (int p = 0; p < 2; ++p) {
        int idx = p*512 + tid;                  // 0..1023
        int n = idx >> 4, q = idx & 15;
        float4 hv = make_float4(0.f,0.f,0.f,0.f), av = make_float4(0.f,0.f,0.f,0.f);
        if (base4 + idx < Nn*16) {
            hv = out4[base4 + idx];
            av = agg4[base4 + idx];
            agg4[base4 + idx] = make_float4(0.f,0.f,0.f,0.f);
        }
        int slot = (q ^ ((n & 7) << 1)) << 2;
        *(float4*)(hN + n*68 + slot) = hv;
        *(float4*)(mN + n*68 + slot) = av;
    }
    __syncthreads();

    // h row -> 64 VGPRs (static indexing)
    float4 hreg[16];
    const float* hrow = hN + lane*68;
    const float* mrow = mN + lane*68;
    #pragma unroll
    for (int i4 = 0; i4 < 16; ++i4)
        hreg[i4] = *(const float4*)(hrow + ((i4 ^ sw) << 2));

    const float* wA = wAt + ob;
    const float* wB = wBt + ob;
    float a0[8], a1[8], r[8], z[8];

    // P1: root matvec; m = relu(root + agg + convb) -> mN (in-place over agg)
    #pragma unroll
    for (int j = 0; j < 8; ++j) a0[j] = 0.f;
    mv8h(hreg, wA, a0);
    #pragma unroll
    for (int j = 0; j < 8; ++j) {
        int c = ob + j;
        int off = lane*68 + (((c >> 2) ^ sw) << 2) + (c & 3);
        float mval = fmaxf(a0[j] + mN[off] + convb[c], 0.f);
        mN[off] = mval;
    }
    __syncthreads();   // mN complete

    // P2: r gate (gi_r + gh_r into one acc)
    #pragma unroll
    for (int j = 0; j < 8; ++j) a0[j] = gbih[ob+j] + gbhh[ob+j];
    mv8h(hreg, wA + 64, a0);
    mv8m(mrow, sw, wB, a0);
    #pragma unroll
    for (int j = 0; j < 8; ++j) r[j] = sigf(a0[j]);

    // P3: z gate
    #pragma unroll
    for (int j = 0; j < 8; ++j) a0[j] = gbih[64+ob+j] + gbhh[64+ob+j];
    mv8h(hreg, wA + 128, a0);
    mv8m(mrow, sw, wB + 64, a0);
    #pragma unroll
    for (int j = 0; j < 8; ++j) z[j] = sigf(a0[j]);

    // P4: n gate (gh_n, gi_n separate; r scales gh_n only), combine into a0
    #pragma unroll
    for (int j = 0; j < 8; ++j) { a0[j] = gbhh[128+ob+j]; a1[j] = gbih[128+ob+j]; }
    mv8h(hreg, wA + 192, a0);
    mv8m(mrow, sw, wB + 128, a1);
    #pragma unroll
    for (int j = 0; j < 8; ++j) {
        int c = ob + j;
        int off = lane*68 + (((c >> 2) ^ sw) << 2) + (c & 3);
        float nn = tanhf(fmaf(r[j], a0[j], a1[j]));
        float h  = hN[off];
        a0[j] = (1.f - z[j])*nn + z[j]*h;
    }
    __syncthreads();   // all reads of hN/mN done

    #pragma unroll
    for (int j = 0; j < 8; ++j) {
        int c = ob + j;
        int off = lane*68 + (((c >> 2) ^ sw) << 2) + (c & 3);
        hN[off] = a0[j];
    }
    __syncthreads();

    // coalesced out write from swizzled hN
    #pragma unroll
    for (int p = 0; p < 2; ++p) {
        int idx = p*512 + tid;
        int n = idx >> 4, q = idx & 15;
        if (base4 + idx < Nn*16)
            out4[base4 + idx] = *(const float4*)(hN + n*68 + ((q ^ ((n & 7) << 1)) << 2));
    }
}

// one launch per Set2Set iteration: every block redundantly finalizes prev partials
// + runs the tiny LSTM (identical f32 math in all blocks), then computes its
// online-softmax partials with the fresh hs. Double-buffered partials (rd/wr).
__global__ __launch_bounds__(256) void k_s2s(
        const float* __restrict__ wih, const float* __restrict__ whh,
        const float* __restrict__ bih, const float* __restrict__ bhh,
        float* __restrict__ hs, float* __restrict__ cs,
        const float* __restrict__ out,
        const float* __restrict__ gmax_rd, const float* __restrict__ gsum_rd,
        const float* __restrict__ gr_rd,
        float* __restrict__ gmax_wr, float* __restrict__ gsum_wr,
        float* __restrict__ gr_wr, int it) {
    __shared__ float red[256], shs[64], scs[64], srv[64], sg[256];
    __shared__ float sm_m[4], sm_z[4], sm_r[4][64];
    int tid = threadIdx.x, lane = tid & 63, w = tid >> 6;

    if (it == 0) {
        if (tid < 64) { shs[tid] = 0.f; scs[tid] = 0.f; srv[tid] = 0.f; }
    } else {
        float gm = gmax_rd[tid];
        red[tid] = gm; __syncthreads();
        for (int s = 128; s > 0; s >>= 1) { if (tid < s) red[tid] = fmaxf(red[tid], red[tid+s]); __syncthreads(); }
        float M = red[0]; __syncthreads();
        red[tid] = gsum_rd[tid] * expf(gm - M); __syncthreads();
        for (int s = 128; s > 0; s >>= 1) { if (tid < s) red[tid] += red[tid+s]; __syncthreads(); }
        float Z = red[0]; __syncthreads();
        float racc = 0.f;
        for (int b = w; b < 256; b += 4) racc = fmaf(gr_rd[b*64 + lane], expf(gmax_rd[b] - M), racc);
        red[tid] = racc; __syncthreads();
        if (w == 0) srv[lane] = (red[lane] + red[64+lane] + red[128+lane] + red[192+lane]) / Z;
        if (tid < 64) { shs[tid] = hs[tid]; scs[tid] = cs[tid]; }
    }
    __syncthreads();

    // LSTM: g[tid] over 256 gates
    {
        const float* wi = wih + tid*128;
        const float* wh = whh + tid*64;
        float g = bih[tid] + bhh[tid];
        #pragma unroll 8
        for (int i = 0; i < 64; ++i) g += shs[i]*(wi[i] + wh[i]) + srv[i]*wi[64+i];
        sg[tid] = g;
    }
    __syncthreads();
    if (tid < 64) {
        float ii = sigf(sg[tid]), ff = sigf(sg[64+tid]);
        float gg = tanhf(sg[128+tid]), oo = sigf(sg[192+tid]);
        float c2 = ff*scs[tid] + ii*gg;
        float hn = oo*tanhf(c2);
        shs[tid] = hn;
        if (blockIdx.x == 0) { hs[tid] = hn; cs[tid] = c2; }
    }
    __syncthreads();

    // online-softmax partials with fresh hs
    float hsv = shs[lane];
    float m = -3.4e38f, Z2 = 0.f, racc2 = 0.f;
    for (int n = blockIdx.x*4 + w; n < Nn; n += 1024) {
        float ov = out[n*64 + lane];
        float p = ov * hsv;
        #pragma unroll
        for (int off = 32; off > 0; off >>= 1) p += __shfl_xor(p, off, 64);
        float mn = fmaxf(m, p);
        float sc = expf(m - mn);
        float t  = expf(p - mn);
        Z2 = fmaf(Z2, sc, t);
        racc2 = fmaf(racc2, sc, t*ov);
        m = mn;
    }
    if (lane == 0) { sm_m[w] = m; sm_z[w] = Z2; }
    sm_r[w][lane] = racc2;
    __syncthreads();
    if (w == 0) {
        float M = fmaxf(fmaxf(sm_m[0], sm_m[1]), fmaxf(sm_m[2], sm_m[3]));
        float Zb = 0.f, rb = 0.f;
        #pragma unroll
        for (int j = 0; j < 4; ++j) {
            float e = expf(sm_m[j] - M);
            Zb = fmaf(sm_z[j], e, Zb);
            rb = fmaf(sm_r[j][lane], e, rb);
        }
        gr_wr[blockIdx.x*64 + lane] = rb;
        if (lane == 0) { gmax_wr[blockIdx.x] = M; gsum_wr[blockIdx.x] = Zb; }
    }
}

// final: finalize rv, mem-LSTM (h=c=0), lin1, lin3 -> dout = [v, hx(64), cx(64)]
__global__ __launch_bounds__(256) void k_final2(const float* __restrict__ mwih,
        const float* __restrict__ mbih, const float* __restrict__ mbhh,
        const float* __restrict__ hs,
        const float* __restrict__ gmax, const float* __restrict__ gsum,
        const float* __restrict__ gr,
        const float* __restrict__ l1w, const float* __restrict__ l1b,
        const float* __restrict__ l3w, const float* __restrict__ l3b,
        float* __restrict__ dout) {
    __shared__ float red[256], shs[64], srv[64], sg[256], shx[64], so[64];
    int tid = threadIdx.x, lane = tid & 63, w = tid >> 6;
    {
        float gm = gmax[tid];
        red[tid] = gm; __syncthreads();
        for (int s = 128; s > 0; s >>= 1) { if (tid < s) red[tid] = fmaxf(red[tid], red[tid+s]); __syncthreads(); }
        float M = red[0]; __syncthreads();
        red[tid] = gsum[tid] * expf(gm - M); __syncthreads();
        for (int s = 128; s > 0; s >>= 1) { if (tid < s) red[tid] += red[tid+s]; __syncthreads(); }
        float Z = red[0]; __syncthreads();
        float racc = 0.f;
        for (int b = w; b < 256; b += 4) racc = fmaf(gr[b*64 + lane], expf(gmax[b] - M), racc);
        red[tid] = racc; __syncthreads();
        if (w == 0) srv[lane] = (red[lane] + red[64+lane] + red[128+lane] + red[192+lane]) / Z;
        if (tid < 64) shs[tid] = hs[tid];
    }
    __syncthreads();
    const float* wi = mwih + tid*128;
    float g = mbih[tid] + mbhh[tid];
    #pragma unroll 8
    for (int i = 0; i < 64; ++i) g += shs[i]*wi[i] + srv[i]*wi[64+i];
    sg[tid] = g; __syncthreads();
    if (tid < 64) {
        float ii = sigf(sg[tid]);
        float gg = tanhf(sg[128+tid]);
        float oo = sigf(sg[192+tid]);
        float c2 = ii * gg;
        float hx = oo * tanhf(c2);
        shx[tid] = hx;
        dout[1 + tid] = hx;
        dout[65 + tid] = c2;
    }
    __syncthreads();
    if (tid < 64) {
        float a = l1b[tid];
        const float* wr = l1w + tid*64;
        #pragma unroll 8
        for (int i = 0; i < 64; ++i) a = fmaf(shx[i], wr[i], a);
        so[tid] = fmaxf(a, 0.f);
    }
    __syncthreads();
    if (tid == 0) {
        float v = l3b[0];
        for (int i = 0; i < 64; ++i) v = fmaf(so[i], l3w[i], v);
        dout[0] = v;
    }
}

extern "C" void kernel_launch(void* const* d_in, const int* in_sizes, int n_in,
                              void* d_out, int out_size, void* d_ws, size_t ws_size,
                              hipStream_t stream) {
    const float* x    = (const float*)d_in[0];
    const int*   ei   = (const int*)  d_in[1];
    const float* ea   = (const float*)d_in[2];
    const float* l0w  = (const float*)d_in[3];
    const float* l0b  = (const float*)d_in[4];
    const float* e1w  = (const float*)d_in[5];
    const float* e1b  = (const float*)d_in[6];
    const float* e2w  = (const float*)d_in[7];
    const float* e2b  = (const float*)d_in[8];
    const float* rootw= (const float*)d_in[9];
    const float* convb= (const float*)d_in[10];
    const float* gwih = (const float*)d_in[11];
    const float* gwhh = (const float*)d_in[12];
    const float* gbih = (const float*)d_in[13];
    const float* gbhh = (const float*)d_in[14];
    const float* swih = (const float*)d_in[15];
    const float* swhh = (const float*)d_in[16];
    const float* sbih = (const float*)d_in[17];
    const float* sbhh = (const float*)d_in[18];
    const float* mwih = (const float*)d_in[19];
    const float* mbih = (const float*)d_in[21];
    const float* mbhh = (const float*)d_in[22];
    const float* l1w  = (const float*)d_in[23];
    const float* l1b  = (const float*)d_in[24];
    const float* l3w  = (const float*)d_in[25];
    const float* l3b  = (const float*)d_in[26];

    float* ws   = (float*)d_ws;
    float* dout = (float*)d_out;
    if (ws_size < (size_t)WS_FLOATS * sizeof(float)) return;

    float* agg  = ws + OFF_AGG;
    float* deg  = ws + OFF_DEG;
    float* out  = ws + OFF_OUT;
    float* dinv = ws + OFF_DINV;
    float* At   = ws + OFF_AT;
    float* Bt   = ws + OFF_BT;
    float* bp   = ws + OFF_BP;
    float* ubuf = ws + OFF_U;
    float* vbuf = ws + OFF_V;
    int*   mc   = (int*)(ws + OFF_MC);
    int*   pe   = (int*)(ws + OFF_PE);
    int*   bh   = (int*)(ws + OFF_BH);
    int*   bc   = (int*)(ws + OFF_BC);
    int*   sS   = (int*)(ws + OFF_SS);
    int*   sD   = (int*)(ws + OFF_SD);
    float* sA   = ws + OFF_SA;
    int*   sP   = (int*)(ws + OFF_SP);
    float* wAt  = ws + OFF_WAT;
    float* wBt  = ws + OFF_WBT;
    float* gmA  = ws + OFF_GMA;
    float* gsA  = ws + OFF_GSA;
    float* grA  = ws + OFF_GRA;
    float* gmB  = ws + OFF_GMB;
    float* gsB  = ws + OFF_GSB;
    float* grB  = ws + OFF_GRB;
    float* hs   = ws + OFF_HS;
    float* cs   = ws + OFF_CS;

    hipMemsetAsync(d_ws, 0, (size_t)ZERO_END * sizeof(float), stream);

    k_lin0    <<<(Nn*64 + 255)/256, 256, 0, stream>>>(x, l0w, l0b, out);
    k_patterns<<<1, 64, 0, stream>>>(e1w, e1b, bp, ubuf, vbuf, mc);
    k_AB      <<<65, 256, 0, stream>>>(e2w, e2b, ubuf, vbuf, mc, At, Bt);
    k_eprep2  <<<NB_E, 256, 0, stream>>>(ei, ea, bp, mc, deg, pe, bh);
    k_scan2   <<<60, 256, 0, stream>>>(deg, dinv, bh, bc);
    k_scatter2<<<NB_E, 256, 0, stream>>>(ei, ea, pe, bc, sS, sD, sA, sP);
    k_wt      <<<(16384 + 12288 + 255)/256, 256, 0, stream>>>(rootw, gwhh, gwih, wAt, wBt);

    for (int s = 0; s < 6; ++s) {
        k_edge3<<<EB, 256, 0, stream>>>(sS, sD, sA, sP, out, At, Bt, dinv, agg);
        k_gru5 <<<(Nn + 63)/64, 512, 0, stream>>>(out, agg, wAt, wBt, convb, gbih, gbhh);
    }

    for (int it = 0; it < 6; ++it) {
        float* gm_rd = (it & 1) ? gmA : gmB;   // unused at it=0
        float* gs_rd = (it & 1) ? gsA : gsB;
        float* gr_rd = (it & 1) ? grA : grB;
        float* gm_wr = (it & 1) ? gmB : gmA;
        float* gs_wr = (it & 1) ? gsB : gsA;
        float* gr_wr = (it & 1) ? grB : grA;
        k_s2s<<<256, 256, 0, stream>>>(swih, swhh, sbih, sbhh, hs, cs, out,
                                       gm_rd, gs_rd, gr_rd, gm_wr, gs_wr, gr_wr, it);
    }

    // it=5 wrote the B buffers
    k_final2<<<1, 256, 0, stream>>>(mwih, mbih, mbhh, hs, gmB, gsB, grB,
                                    l1w, l1b, l3w, l3b, dout);
}

// Round 7
// 699.832 us; speedup vs baseline: 4.2919x; 1.1118x over previous
//
#include <hip/hip_runtime.h>
#include <math.h>

#define Nn 15000
#define Ee 30000
#define NB_E 118   // ceil(Ee/256)
#define EB 768     // k_edge3 blocks

// ---- workspace layout (float offsets) ----
// zero region (memset each call):
#define OFF_AGG   0          // [Nn*64]
#define OFF_DEG   960000     // [Nn]
#define ZERO_END  975000
// written-before-read region:
#define OFF_OUT   975008     // [Nn*64]
#define OFF_DINV  1935008    // [Nn]
#define OFF_AT    1950016    // [65*4096] transposed: At[p][o*64+i]
#define OFF_BT    2216256    // [65*4096]
#define OFF_BP    2482496    // [64]
#define OFF_U     2482560    // [65*64]
#define OFF_V     2486720    // [65*64]
#define OFF_MC    2490880    // [1] int
#define OFF_PE    2490884    // [Ee] int
#define OFF_BH    2520884    // [NB_E*65] int per-block hist
#define OFF_BC    2528554    // [NB_E*65] int per-block cursors
#define OFF_SS    2536224    // [Ee] int
#define OFF_SD    2566224    // [Ee] int
#define OFF_SA    2596224    // [Ee] float
#define OFF_SP    2626224    // [Ee] int
#define OFF_PK    2656224    // [7*4096] packed GRU weights pk[g][i4][lane][k]
#define OFF_GMA   2684896    // [256]
#define OFF_GSA   2685152    // [256]
#define OFF_GRA   2685408    // [256*64]
#define OFF_GMB   2701792    // [256]
#define OFF_GSB   2702048    // [256]
#define OFF_GRB   2702304    // [256*64]
#define OFF_HS    2718688    // [64]
#define OFF_CS    2718752    // [64]
#define WS_FLOATS 2718816

__device__ __forceinline__ float sigf(float x) { return 1.0f / (1.0f + expf(-x)); }
__device__ __forceinline__ float bcast(float v, int l) {
    return __int_as_float(__builtin_amdgcn_readlane(__float_as_int(v), l));
}

__global__ void k_lin0(const float* __restrict__ x, const float* __restrict__ w,
                       const float* __restrict__ b, float* __restrict__ out) {
    int idx = blockIdx.x * 256 + threadIdx.x;
    if (idx >= Nn * 64) return;
    int n = idx >> 6, o = idx & 63;
    float v = b[o] + x[n*3+0]*w[o*3+0] + x[n*3+1]*w[o*3+1] + x[n*3+2]*w[o*3+2];
    out[idx] = fmaxf(v, 0.0f);
}

// he[e,k] = relu(a*w1[k]+b1[k]) piecewise-linear in scalar a: <=64 breakpoints.
__global__ void k_patterns(const float* __restrict__ e1w, const float* __restrict__ e1b,
                           float* __restrict__ bp, float* __restrict__ u,
                           float* __restrict__ v, int* __restrict__ mc) {
    __shared__ float t[64]; __shared__ int valid[64]; __shared__ float sbp[65]; __shared__ int cnt;
    int k = threadIdx.x;
    float w1 = e1w[k], b1 = e1b[k];
    float tv = 0.f; int va = 0;
    if (w1 != 0.f) { tv = -b1 / w1; va = (tv > 0.f && tv < 1.f) ? 1 : 0; }
    t[k] = tv; valid[k] = va;
    __syncthreads();
    if (va) {
        int rank = 0;
        for (int kk = 0; kk < 64; ++kk)
            if (valid[kk] && (t[kk] < tv || (t[kk] == tv && kk < k))) rank++;
        sbp[rank] = tv;
    }
    if (k == 0) { int c = 0; for (int kk = 0; kk < 64; ++kk) c += valid[kk]; cnt = c; *mc = c; }
    __syncthreads();
    int m = cnt;
    if (k < m) bp[k] = sbp[k];
    for (int j = 0; j <= m; ++j) {
        float lo = (j == 0) ? 0.f : sbp[j-1];
        float hi = (j == m) ? 1.f : sbp[j];
        float c = 0.5f * (lo + hi);
        int msk = (c * w1 + b1) > 0.f;
        u[j*64 + k] = msk ? w1 : 0.f;
        v[j*64 + k] = msk ? b1 : 0.f;
    }
}

// transposed outputs: At[j][o*64+i] = sum_k u_j[k]*e2w[(i*64+o)*64+k]; Bt likewise + e2b
__global__ void k_AB(const float* __restrict__ e2w, const float* __restrict__ e2b,
                     const float* __restrict__ u, const float* __restrict__ v,
                     const int* __restrict__ mc, float* __restrict__ At, float* __restrict__ Bt) {
    int j = blockIdx.x;
    if (j > *mc) return;
    __shared__ float su[64], sv[64];
    if (threadIdx.x < 64) { su[threadIdx.x] = u[j*64+threadIdx.x]; sv[threadIdx.x] = v[j*64+threadIdx.x]; }
    __syncthreads();
    for (int q = threadIdx.x; q < 4096; q += 256) {
        int i = q >> 6, o = q & 63;
        const float* row = e2w + q*64;
        float a = 0.f, b = 0.f;
        #pragma unroll 8
        for (int k = 0; k < 64; ++k) { float w = row[k]; a = fmaf(su[k], w, a); b = fmaf(sv[k], w, b); }
        At[j*4096 + o*64 + i] = a;
        Bt[j*4096 + o*64 + i] = b + e2b[q];
    }
}

// per-block LDS histogram (no global hist atomics) + deg + classify
__global__ void k_eprep2(const int* __restrict__ ei, const float* __restrict__ ea,
                         const float* __restrict__ bp, const int* __restrict__ mc,
                         float* __restrict__ deg, int* __restrict__ pe, int* __restrict__ bh) {
    __shared__ int lh[65];
    int tid = threadIdx.x;
    if (tid < 65) lh[tid] = 0;
    __syncthreads();
    int e = blockIdx.x * 256 + tid;
    if (e < Ee) {
        atomicAdd(&deg[ei[Ee + e]], 1.0f);
        float a = ea[e];
        int m = *mc, p = 0;
        for (int j = 0; j < m; ++j) p += (bp[j] <= a) ? 1 : 0;
        pe[e] = p;
        atomicAdd(&lh[p], 1);
    }
    __syncthreads();
    if (tid < 65) bh[blockIdx.x*65 + tid] = lh[tid];
}

// blocks 0..58: dinv; block 59: two-level scan -> per-block per-bin cursors
__global__ void k_scan2(const float* __restrict__ deg, float* __restrict__ dinv,
                        const int* __restrict__ bh, int* __restrict__ bc) {
    int tid = threadIdx.x;
    if (blockIdx.x < 59) {
        int n = blockIdx.x * 256 + tid;
        if (n < Nn) dinv[n] = 1.0f / fmaxf(deg[n], 1.0f);
        return;
    }
    __shared__ int stot[65]; __shared__ int sbase[65];
    if (tid < 65) {
        int t = 0;
        for (int b = 0; b < NB_E; ++b) t += bh[b*65 + tid];
        stot[tid] = t;
    }
    __syncthreads();
    if (tid == 0) {
        int run = 0;
        for (int j = 0; j < 65; ++j) { sbase[j] = run; run += stot[j]; }
    }
    __syncthreads();
    if (tid < 65) {
        int run = sbase[tid];
        for (int b = 0; b < NB_E; ++b) { bc[b*65 + tid] = run; run += bh[b*65 + tid]; }
    }
}

// scatter using per-block LDS cursors (LDS atomics only)
__global__ void k_scatter2(const int* __restrict__ ei, const float* __restrict__ ea,
                           const int* __restrict__ pe, const int* __restrict__ bc,
                           int* __restrict__ sS, int* __restrict__ sD,
                           float* __restrict__ sA, int* __restrict__ sP) {
    __shared__ int cur[65];
    int tid = threadIdx.x;
    if (tid < 65) cur[tid] = bc[blockIdx.x*65 + tid];
    __syncthreads();
    int e = blockIdx.x * 256 + tid;
    if (e >= Ee) return;
    int p = pe[e];
    int pos = atomicAdd(&cur[p], 1);
    sS[pos] = ei[e]; sD[pos] = ei[Ee + e]; sA[pos] = ea[e]; sP[pos] = p;
}

// packed GRU weights for VGPR-resident matvecs:
// pk[g*4096 + i4*256 + lane*4 + k] = Wg[i4*4+k][lane]
// g: 0=root (rootw[i][o]); 1..3 = whh gates r,z,n; 4..6 = wih gates r,z,n
__global__ void k_wt2(const float* __restrict__ rootw, const float* __restrict__ whh,
                      const float* __restrict__ wih, float* __restrict__ pk) {
    int idx = blockIdx.x * 256 + threadIdx.x;
    if (idx >= 7*4096) return;
    int g = idx >> 12;
    int t = idx & 4095;
    int q4 = t >> 2, k = t & 3;
    int lane = q4 & 63;
    int i4 = q4 >> 6;
    int i = i4*4 + k;
    float v;
    if (g == 0)      v = rootw[i*64 + lane];
    else if (g < 4)  v = whh[((g-1)*64 + lane)*64 + i];
    else             v = wih[((g-4)*64 + lane)*64 + i];
    pk[idx] = v;
}

// pattern-sorted edges, VGPR-cached pattern columns (float4 reload from transposed At/Bt)
__global__ __launch_bounds__(256) void k_edge3(
        const int* __restrict__ sS, const int* __restrict__ sD,
        const float* __restrict__ sA, const int* __restrict__ sP,
        const float* __restrict__ out, const float* __restrict__ At,
        const float* __restrict__ Bt, const float* __restrict__ dinv,
        float* __restrict__ agg) {
    int tid = threadIdx.x, lane = tid & 63;
    int wid = (blockIdx.x * 256 + tid) >> 6;       // 0..EB*4-1
    const int NW = EB * 4;
    const int CH = (Ee + NW - 1) / NW;
    int e0 = wid * CH;
    int e1 = e0 + CH; if (e1 > Ee) e1 = Ee;
    float Ar[64], Br[64];
    int curp = -1;
    for (int e = e0; e < e1; ++e) {
        int p = sP[e];
        if (p != curp) {
            curp = p;
            const float4* Ap4 = (const float4*)(At + p*4096 + lane*64);
            const float4* Bp4 = (const float4*)(Bt + p*4096 + lane*64);
            #pragma unroll
            for (int q = 0; q < 16; ++q) {
                float4 av = Ap4[q], bv = Bp4[q];
                Ar[q*4+0]=av.x; Ar[q*4+1]=av.y; Ar[q*4+2]=av.z; Ar[q*4+3]=av.w;
                Br[q*4+0]=bv.x; Br[q*4+1]=bv.y; Br[q*4+2]=bv.z; Br[q*4+3]=bv.w;
            }
        }
        int src = sS[e], dst = sD[e];
        float a = sA[e];
        float hv = out[src*64 + lane];
        float acc0 = 0.f, acc1 = 0.f;
        #pragma unroll
        for (int i = 0; i < 64; i += 2) {
            float h0 = bcast(hv, i);
            float h1 = bcast(hv, i+1);
            acc0 = fmaf(h0, fmaf(a, Ar[i],   Br[i]),   acc0);
            acc1 = fmaf(h1, fmaf(a, Ar[i+1], Br[i+1]), acc1);
        }
        float acc = (acc0 + acc1) * dinv[dst];
        atomicAdd(&agg[dst*64 + lane], acc);
    }
}

// fused NNConv-root + full GRU, k_edge3-style: weights VGPR-resident per wave,
// operand broadcast via v_readlane from registers. 32-node tile, 8 waves:
// phase A = 4 gates{root,ghr,ghz,ghn} x 2 halves; phase B = 3 gi gates x 2 halves.
// Gates cross waves via 5 LDS buffers (40KB, stride-64 conflict-free).
__global__ __launch_bounds__(512, 4) void k_gru7(
        float* __restrict__ out, float* __restrict__ agg,
        const float* __restrict__ pk, const float* __restrict__ convb,
        const float* __restrict__ gbih, const float* __restrict__ gbhh) {
    __shared__ float mL[2048];   // m[ln][c]
    __shared__ float gA[2048];   // gh_r -> r
    __shared__ float gB[2048];   // gh_z -> z
    __shared__ float gC[2048];   // gh_n (raw)
    __shared__ float gD[2048];   // gi_n + bih_n
    int tid = threadIdx.x, lane = tid & 63;
    int w = tid >> 6;
    int n0 = blockIdx.x * 32;
    const float4* pk4 = (const float4*)pk;

    float4 wreg[16];
    int g = w >> 1, hf = w & 1;

    // ---- phase A: root, gh_r, gh_z, gh_n ----
    #pragma unroll
    for (int i4 = 0; i4 < 16; ++i4) wreg[i4] = pk4[(g*16 + i4)*64 + lane];

    int nb0 = n0 + hf*16;
    float cbv = convb[lane];
    for (int nb = 0; nb < 16; nb += 4) {
        int n = nb0 + nb;
        float hv0 = (n+0 < Nn) ? out[(n+0)*64 + lane] : 0.f;
        float hv1 = (n+1 < Nn) ? out[(n+1)*64 + lane] : 0.f;
        float hv2 = (n+2 < Nn) ? out[(n+2)*64 + lane] : 0.f;
        float hv3 = (n+3 < Nn) ? out[(n+3)*64 + lane] : 0.f;
        float a0 = 0.f, a1 = 0.f, a2 = 0.f, a3 = 0.f;
        #pragma unroll
        for (int i4 = 0; i4 < 16; ++i4) {
            float4 wv = wreg[i4];
            a0 = fmaf(bcast(hv0, i4*4+0), wv.x, a0);
            a1 = fmaf(bcast(hv1, i4*4+0), wv.x, a1);
            a2 = fmaf(bcast(hv2, i4*4+0), wv.x, a2);
            a3 = fmaf(bcast(hv3, i4*4+0), wv.x, a3);
            a0 = fmaf(bcast(hv0, i4*4+1), wv.y, a0);
            a1 = fmaf(bcast(hv1, i4*4+1), wv.y, a1);
            a2 = fmaf(bcast(hv2, i4*4+1), wv.y, a2);
            a3 = fmaf(bcast(hv3, i4*4+1), wv.y, a3);
            a0 = fmaf(bcast(hv0, i4*4+2), wv.z, a0);
            a1 = fmaf(bcast(hv1, i4*4+2), wv.z, a1);
            a2 = fmaf(bcast(hv2, i4*4+2), wv.z, a2);
            a3 = fmaf(bcast(hv3, i4*4+2), wv.z, a3);
            a0 = fmaf(bcast(hv0, i4*4+3), wv.w, a0);
            a1 = fmaf(bcast(hv1, i4*4+3), wv.w, a1);
            a2 = fmaf(bcast(hv2, i4*4+3), wv.w, a2);
            a3 = fmaf(bcast(hv3, i4*4+3), wv.w, a3);
        }
        int ln = n - n0;
        float ac[4] = {a0, a1, a2, a3};
        if (g == 0) {
            #pragma unroll
            for (int k2 = 0; k2 < 4; ++k2) {
                float mval = 0.f;
                if (n + k2 < Nn) {
                    float av = agg[(n+k2)*64 + lane];
                    agg[(n+k2)*64 + lane] = 0.f;
                    mval = fmaxf(ac[k2] + av + cbv, 0.f);
                }
                mL[(ln+k2)*64 + lane] = mval;
            }
        } else {
            float* gbuf = (g == 1) ? gA : (g == 2) ? gB : gC;
            #pragma unroll
            for (int k2 = 0; k2 < 4; ++k2) gbuf[(ln+k2)*64 + lane] = ac[k2];
        }
    }
    __syncthreads();

    // ---- phase B: gi_r, gi_z, gi_n (waves 0..5) ----
    if (w < 6) {
        int gb = w >> 1, hf2 = w & 1;
        #pragma unroll
        for (int i4 = 0; i4 < 16; ++i4) wreg[i4] = pk4[((4+gb)*16 + i4)*64 + lane];
        float bsum = (gb == 0) ? (gbih[lane] + gbhh[lane])
                   : (gb == 1) ? (gbih[64+lane] + gbhh[64+lane])
                   : gbih[128+lane];
        int lb0 = hf2*16;
        for (int nb = 0; nb < 16; nb += 4) {
            int ln = lb0 + nb;
            float mv0 = mL[(ln+0)*64 + lane];
            float mv1 = mL[(ln+1)*64 + lane];
            float mv2 = mL[(ln+2)*64 + lane];
            float mv3 = mL[(ln+3)*64 + lane];
            float a0 = 0.f, a1 = 0.f, a2 = 0.f, a3 = 0.f;
            #pragma unroll
            for (int i4 = 0; i4 < 16; ++i4) {
                float4 wv = wreg[i4];
                a0 = fmaf(bcast(mv0, i4*4+0), wv.x, a0);
                a1 = fmaf(bcast(mv1, i4*4+0), wv.x, a1);
                a2 = fmaf(bcast(mv2, i4*4+0), wv.x, a2);
                a3 = fmaf(bcast(mv3, i4*4+0), wv.x, a3);
                a0 = fmaf(bcast(mv0, i4*4+1), wv.y, a0);
                a1 = fmaf(bcast(mv1, i4*4+1), wv.y, a1);
                a2 = fmaf(bcast(mv2, i4*4+1), wv.y, a2);
                a3 = fmaf(bcast(mv3, i4*4+1), wv.y, a3);
                a0 = fmaf(bcast(mv0, i4*4+2), wv.z, a0);
                a1 = fmaf(bcast(mv1, i4*4+2), wv.z, a1);
                a2 = fmaf(bcast(mv2, i4*4+2), wv.z, a2);
                a3 = fmaf(bcast(mv3, i4*4+2), wv.z, a3);
                a0 = fmaf(bcast(mv0, i4*4+3), wv.w, a0);
                a1 = fmaf(bcast(mv1, i4*4+3), wv.w, a1);
                a2 = fmaf(bcast(mv2, i4*4+3), wv.w, a2);
                a3 = fmaf(bcast(mv3, i4*4+3), wv.w, a3);
            }
            float ac[4] = {a0, a1, a2, a3};
            if (gb == 0) {
                #pragma unroll
                for (int k2 = 0; k2 < 4; ++k2) {
                    int r = (ln+k2)*64 + lane;
                    gA[r] = sigf(ac[k2] + gA[r] + bsum);
                }
            } else if (gb == 1) {
                #pragma unroll
                for (int k2 = 0; k2 < 4; ++k2) {
                    int r = (ln+k2)*64 + lane;
                    gB[r] = sigf(ac[k2] + gB[r] + bsum);
                }
            } else {
                #pragma unroll
                for (int k2 = 0; k2 < 4; ++k2)
                    gD[(ln+k2)*64 + lane] = ac[k2] + bsum;
            }
        }
    }
    __syncthreads();

    // ---- combine ----
    float bhn = gbhh[128 + lane];
    #pragma unroll
    for (int p = 0; p < 4; ++p) {
        int site = p*512 + tid;          // 0..2047, c == lane
        int ln = site >> 6;
        int n = n0 + ln;
        if (n < Nn) {
            int r4 = ln*64 + lane;
            float r = gA[r4], z = gB[r4];
            float nn = tanhf(fmaf(r, gC[r4] + bhn, gD[r4]));
            float h = out[n*64 + lane];
            out[n*64 + lane] = (1.f - z)*nn + z*h;
        }
    }
}

// one launch per Set2Set iteration: every block redundantly finalizes prev partials
// + runs the tiny LSTM (identical f32 math in all blocks), then computes its
// online-softmax partials with the fresh hs. Double-buffered partials (rd/wr).
__global__ __launch_bounds__(256) void k_s2s(
        const float* __restrict__ wih, const float* __restrict__ whh,
        const float* __restrict__ bih, const float* __restrict__ bhh,
        float* __restrict__ hs, float* __restrict__ cs,
        const float* __restrict__ out,
        const float* __restrict__ gmax_rd, const float* __restrict__ gsum_rd,
        const float* __restrict__ gr_rd,
        float* __restrict__ gmax_wr, float* __restrict__ gsum_wr,
        float* __restrict__ gr_wr, int it) {
    __shared__ float red[256], shs[64], scs[64], srv[64], sg[256];
    __shared__ float sm_m[4], sm_z[4], sm_r[4][64];
    int tid = threadIdx.x, lane = tid & 63, w = tid >> 6;

    if (it == 0) {
        if (tid < 64) { shs[tid] = 0.f; scs[tid] = 0.f; srv[tid] = 0.f; }
    } else {
        float gm = gmax_rd[tid];
        red[tid] = gm; __syncthreads();
        for (int s = 128; s > 0; s >>= 1) { if (tid < s) red[tid] = fmaxf(red[tid], red[tid+s]); __syncthreads(); }
        float M = red[0]; __syncthreads();
        red[tid] = gsum_rd[tid] * expf(gm - M); __syncthreads();
        for (int s = 128; s > 0; s >>= 1) { if (tid < s) red[tid] += red[tid+s]; __syncthreads(); }
        float Z = red[0]; __syncthreads();
        float racc = 0.f;
        for (int b = w; b < 256; b += 4) racc = fmaf(gr_rd[b*64 + lane], expf(gmax_rd[b] - M), racc);
        red[tid] = racc; __syncthreads();
        if (w == 0) srv[lane] = (red[lane] + red[64+lane] + red[128+lane] + red[192+lane]) / Z;
        if (tid < 64) { shs[tid] = hs[tid]; scs[tid] = cs[tid]; }
    }
    __syncthreads();

    // LSTM: g[tid] over 256 gates
    {
        const float* wi = wih + tid*128;
        const float* wh = whh + tid*64;
        float g = bih[tid] + bhh[tid];
        #pragma unroll 8
        for (int i = 0; i < 64; ++i) g += shs[i]*(wi[i] + wh[i]) + srv[i]*wi[64+i];
        sg[tid] = g;
    }
    __syncthreads();
    if (tid < 64) {
        float ii = sigf(sg[tid]), ff = sigf(sg[64+tid]);
        float gg = tanhf(sg[128+tid]), oo = sigf(sg[192+tid]);
        float c2 = ff*scs[tid] + ii*gg;
        float hn = oo*tanhf(c2);
        shs[tid] = hn;
        if (blockIdx.x == 0) { hs[tid] = hn; cs[tid] = c2; }
    }
    __syncthreads();

    // online-softmax partials with fresh hs
    float hsv = shs[lane];
    float m = -3.4e38f, Z2 = 0.f, racc2 = 0.f;
    for (int n = blockIdx.x*4 + w; n < Nn; n += 1024) {
        float ov = out[n*64 + lane];
        float p = ov * hsv;
        #pragma unroll
        for (int off = 32; off > 0; off >>= 1) p += __shfl_xor(p, off, 64);
        float mn = fmaxf(m, p);
        float sc = expf(m - mn);
        float t  = expf(p - mn);
        Z2 = fmaf(Z2, sc, t);
        racc2 = fmaf(racc2, sc, t*ov);
        m = mn;
    }
    if (lane == 0) { sm_m[w] = m; sm_z[w] = Z2; }
    sm_r[w][lane] = racc2;
    __syncthreads();
    if (w == 0) {
        float M = fmaxf(fmaxf(sm_m[0], sm_m[1]), fmaxf(sm_m[2], sm_m[3]));
        float Zb = 0.f, rb = 0.f;
        #pragma unroll
        for (int j = 0; j < 4; ++j) {
            float e = expf(sm_m[j] - M);
            Zb = fmaf(sm_z[j], e, Zb);
            rb = fmaf(sm_r[j][lane], e, rb);
        }
        gr_wr[blockIdx.x*64 + lane] = rb;
        if (lane == 0) { gmax_wr[blockIdx.x] = M; gsum_wr[blockIdx.x] = Zb; }
    }
}

// final: finalize rv, mem-LSTM (h=c=0), lin1, lin3 -> dout = [v, hx(64), cx(64)]
__global__ __launch_bounds__(256) void k_final2(const float* __restrict__ mwih,
        const float* __restrict__ mbih, const float* __restrict__ mbhh,
        const float* __restrict__ hs,
        const float* __restrict__ gmax, const float* __restrict__ gsum,
        const float* __restrict__ gr,
        const float* __restrict__ l1w, const float* __restrict__ l1b,
        const float* __restrict__ l3w, const float* __restrict__ l3b,
        float* __restrict__ dout) {
    __shared__ float red[256], shs[64], srv[64], sg[256], shx[64], so[64];
    int tid = threadIdx.x, lane = tid & 63, w = tid >> 6;
    {
        float gm = gmax[tid];
        red[tid] = gm; __syncthreads();
        for (int s = 128; s > 0; s >>= 1) { if (tid < s) red[tid] = fmaxf(red[tid], red[tid+s]); __syncthreads(); }
        float M = red[0]; __syncthreads();
        red[tid] = gsum[tid] * expf(gm - M); __syncthreads();
        for (int s = 128; s > 0; s >>= 1) { if (tid < s) red[tid] += red[tid+s]; __syncthreads(); }
        float Z = red[0]; __syncthreads();
        float racc = 0.f;
        for (int b = w; b < 256; b += 4) racc = fmaf(gr[b*64 + lane], expf(gmax[b] - M), racc);
        red[tid] = racc; __syncthreads();
        if (w == 0) srv[lane] = (red[lane] + red[64+lane] + red[128+lane] + red[192+lane]) / Z;
        if (tid < 64) shs[tid] = hs[tid];
    }
    __syncthreads();
    const float* wi = mwih + tid*128;
    float g = mbih[tid] + mbhh[tid];
    #pragma unroll 8
    for (int i = 0; i < 64; ++i) g += shs[i]*wi[i] + srv[i]*wi[64+i];
    sg[tid] = g; __syncthreads();
    if (tid < 64) {
        float ii = sigf(sg[tid]);
        float gg = tanhf(sg[128+tid]);
        float oo = sigf(sg[192+tid]);
        float c2 = ii * gg;
        float hx = oo * tanhf(c2);
        shx[tid] = hx;
        dout[1 + tid] = hx;
        dout[65 + tid] = c2;
    }
    __syncthreads();
    if (tid < 64) {
        float a = l1b[tid];
        const float* wr = l1w + tid*64;
        #pragma unroll 8
        for (int i = 0; i < 64; ++i) a = fmaf(shx[i], wr[i], a);
        so[tid] = fmaxf(a, 0.f);
    }
    __syncthreads();
    if (tid == 0) {
        float v = l3b[0];
        for (int i = 0; i < 64; ++i) v = fmaf(so[i], l3w[i], v);
        dout[0] = v;
    }
}

extern "C" void kernel_launch(void* const* d_in, const int* in_sizes, int n_in,
                              void* d_out, int out_size, void* d_ws, size_t ws_size,
                              hipStream_t stream) {
    const float* x    = (const float*)d_in[0];
    const int*   ei   = (const int*)  d_in[1];
    const float* ea   = (const float*)d_in[2];
    const float* l0w  = (const float*)d_in[3];
    const float* l0b  = (const float*)d_in[4];
    const float* e1w  = (const float*)d_in[5];
    const float* e1b  = (const float*)d_in[6];
    const float* e2w  = (const float*)d_in[7];
    const float* e2b  = (const float*)d_in[8];
    const float* rootw= (const float*)d_in[9];
    const float* convb= (const float*)d_in[10];
    const float* gwih = (const float*)d_in[11];
    const float* gwhh = (const float*)d_in[12];
    const float* gbih = (const float*)d_in[13];
    const float* gbhh = (const float*)d_in[14];
    const float* swih = (const float*)d_in[15];
    const float* swhh = (const float*)d_in[16];
    const float* sbih = (const float*)d_in[17];
    const float* sbhh = (const float*)d_in[18];
    const float* mwih = (const float*)d_in[19];
    const float* mbih = (const float*)d_in[21];
    const float* mbhh = (const float*)d_in[22];
    const float* l1w  = (const float*)d_in[23];
    const float* l1b  = (const float*)d_in[24];
    const float* l3w  = (const float*)d_in[25];
    const float* l3b  = (const float*)d_in[26];

    float* ws   = (float*)d_ws;
    float* dout = (float*)d_out;
    if (ws_size < (size_t)WS_FLOATS * sizeof(float)) return;

    float* agg  = ws + OFF_AGG;
    float* deg  = ws + OFF_DEG;
    float* out  = ws + OFF_OUT;
    float* dinv = ws + OFF_DINV;
    float* At   = ws + OFF_AT;
    float* Bt   = ws + OFF_BT;
    float* bp   = ws + OFF_BP;
    float* ubuf = ws + OFF_U;
    float* vbuf = ws + OFF_V;
    int*   mc   = (int*)(ws + OFF_MC);
    int*   pe   = (int*)(ws + OFF_PE);
    int*   bh   = (int*)(ws + OFF_BH);
    int*   bc   = (int*)(ws + OFF_BC);
    int*   sS   = (int*)(ws + OFF_SS);
    int*   sD   = (int*)(ws + OFF_SD);
    float* sA   = ws + OFF_SA;
    int*   sP   = (int*)(ws + OFF_SP);
    float* pk   = ws + OFF_PK;
    float* gmA  = ws + OFF_GMA;
    float* gsA  = ws + OFF_GSA;
    float* grA  = ws + OFF_GRA;
    float* gmB  = ws + OFF_GMB;
    float* gsB  = ws + OFF_GSB;
    float* grB  = ws + OFF_GRB;
    float* hs   = ws + OFF_HS;
    float* cs   = ws + OFF_CS;

    hipMemsetAsync(d_ws, 0, (size_t)ZERO_END * sizeof(float), stream);

    k_lin0    <<<(Nn*64 + 255)/256, 256, 0, stream>>>(x, l0w, l0b, out);
    k_patterns<<<1, 64, 0, stream>>>(e1w, e1b, bp, ubuf, vbuf, mc);
    k_AB      <<<65, 256, 0, stream>>>(e2w, e2b, ubuf, vbuf, mc, At, Bt);
    k_eprep2  <<<NB_E, 256, 0, stream>>>(ei, ea, bp, mc, deg, pe, bh);
    k_scan2   <<<60, 256, 0, stream>>>(deg, dinv, bh, bc);
    k_scatter2<<<NB_E, 256, 0, stream>>>(ei, ea, pe, bc, sS, sD, sA, sP);
    k_wt2     <<<(7*4096 + 255)/256, 256, 0, stream>>>(rootw, gwhh, gwih, pk);

    for (int s = 0; s < 6; ++s) {
        k_edge3<<<EB, 256, 0, stream>>>(sS, sD, sA, sP, out, At, Bt, dinv, agg);
        k_gru7 <<<(Nn + 31)/32, 512, 0, stream>>>(out, agg, pk, convb, gbih, gbhh);
    }

    for (int it = 0; it < 6; ++it) {
        float* gm_rd = (it & 1) ? gmA : gmB;   // unused at it=0
        float* gs_rd = (it & 1) ? gsA : gsB;
        float* gr_rd = (it & 1) ? grA : grB;
        float* gm_wr = (it & 1) ? gmB : gmA;
        float* gs_wr = (it & 1) ? gsB : gsA;
        float* gr_wr = (it & 1) ? grB : grA;
        k_s2s<<<256, 256, 0, stream>>>(swih, swhh, sbih, sbhh, hs, cs, out,
                                       gm_rd, gs_rd, gr_rd, gm_wr, gs_wr, gr_wr, it);
    }

    // it=5 wrote the B buffers
    k_final2<<<1, 256, 0, stream>>>(mwih, mbih, mbhh, hs, gmB, gsB, grB,
                                    l1w, l1b, l3w, l3b, dout);
}

// Round 8
// 579.115 us; speedup vs baseline: 5.1866x; 1.2085x over previous
//
#include <hip/hip_runtime.h>
#include <math.h>

#define Nn 15000
#define Ee 30000
#define NB_E 118   // ceil(Ee/256)
#define EB 938     // k_edge4 blocks (3752 waves x 8 edges)

// ---- workspace layout (float offsets) ----
// zero region (memset each call):
#define OFF_AGG   0          // [Nn*64]
#define OFF_DEG   960000     // [Nn]
#define ZERO_END  975000
// written-before-read region:
#define OFF_OUT   975008     // [Nn*64]
#define OFF_DINV  1935008    // [Nn]
#define OFF_AT    1950016    // [65*4096] transposed: At[p][o*64+i]
#define OFF_BT    2216256    // [65*4096]
#define OFF_BP    2482496    // [64]
#define OFF_U     2482560    // [65*64]
#define OFF_V     2486720    // [65*64]
#define OFF_MC    2490880    // [1] int
#define OFF_PE    2490884    // [Ee] int
#define OFF_BH    2520884    // [NB_E*65] int per-block hist
#define OFF_BC    2528554    // [NB_E*65] int per-block cursors
#define OFF_SS    2536224    // [Ee] int
#define OFF_SD    2566224    // [Ee] int
#define OFF_SA    2596224    // [Ee] float
#define OFF_SP    2626224    // [Ee] int
#define OFF_PK    2656224    // [7*4096] packed GRU weights pk[g][i4][lane][k]
#define OFF_GMA   2684896    // [256]
#define OFF_GSA   2685152    // [256]
#define OFF_GRA   2685408    // [256*64]
#define OFF_GMB   2701792    // [256]
#define OFF_GSB   2702048    // [256]
#define OFF_GRB   2702304    // [256*64]
#define OFF_HS    2718688    // [64]
#define OFF_CS    2718752    // [64]
#define WS_FLOATS 2718816

__device__ __forceinline__ float sigf(float x) { return 1.0f / (1.0f + expf(-x)); }
__device__ __forceinline__ float bcast(float v, int l) {
    return __int_as_float(__builtin_amdgcn_readlane(__float_as_int(v), l));
}
__device__ __forceinline__ int bcasti(int v, int l) {
    return __builtin_amdgcn_readlane(v, l);
}

__global__ void k_lin0(const float* __restrict__ x, const float* __restrict__ w,
                       const float* __restrict__ b, float* __restrict__ out) {
    int idx = blockIdx.x * 256 + threadIdx.x;
    if (idx >= Nn * 64) return;
    int n = idx >> 6, o = idx & 63;
    float v = b[o] + x[n*3+0]*w[o*3+0] + x[n*3+1]*w[o*3+1] + x[n*3+2]*w[o*3+2];
    out[idx] = fmaxf(v, 0.0f);
}

// he[e,k] = relu(a*w1[k]+b1[k]) piecewise-linear in scalar a: <=64 breakpoints.
__global__ void k_patterns(const float* __restrict__ e1w, const float* __restrict__ e1b,
                           float* __restrict__ bp, float* __restrict__ u,
                           float* __restrict__ v, int* __restrict__ mc) {
    __shared__ float t[64]; __shared__ int valid[64]; __shared__ float sbp[65]; __shared__ int cnt;
    int k = threadIdx.x;
    float w1 = e1w[k], b1 = e1b[k];
    float tv = 0.f; int va = 0;
    if (w1 != 0.f) { tv = -b1 / w1; va = (tv > 0.f && tv < 1.f) ? 1 : 0; }
    t[k] = tv; valid[k] = va;
    __syncthreads();
    if (va) {
        int rank = 0;
        for (int kk = 0; kk < 64; ++kk)
            if (valid[kk] && (t[kk] < tv || (t[kk] == tv && kk < k))) rank++;
        sbp[rank] = tv;
    }
    if (k == 0) { int c = 0; for (int kk = 0; kk < 64; ++kk) c += valid[kk]; cnt = c; *mc = c; }
    __syncthreads();
    int m = cnt;
    if (k < m) bp[k] = sbp[k];
    for (int j = 0; j <= m; ++j) {
        float lo = (j == 0) ? 0.f : sbp[j-1];
        float hi = (j == m) ? 1.f : sbp[j];
        float c = 0.5f * (lo + hi);
        int msk = (c * w1 + b1) > 0.f;
        u[j*64 + k] = msk ? w1 : 0.f;
        v[j*64 + k] = msk ? b1 : 0.f;
    }
}

// parallel A/B build: grid 65x16, block handles 256 q's of pattern j.
// At[j][o*64+i] = sum_k u_j[k]*e2w[(i*64+o)*64+k]; Bt likewise + e2b
__global__ void k_AB2(const float* __restrict__ e2w, const float* __restrict__ e2b,
                      const float* __restrict__ u, const float* __restrict__ v,
                      const int* __restrict__ mc, float* __restrict__ At, float* __restrict__ Bt) {
    int j = blockIdx.x >> 4;
    if (j > *mc) return;
    int qc = blockIdx.x & 15;
    __shared__ float su[64], sv[64];
    if (threadIdx.x < 64) { su[threadIdx.x] = u[j*64+threadIdx.x]; sv[threadIdx.x] = v[j*64+threadIdx.x]; }
    __syncthreads();
    int q = qc*256 + threadIdx.x;
    int i = q >> 6, o = q & 63;
    const float* row = e2w + q*64;
    float a = 0.f, b = 0.f;
    #pragma unroll 8
    for (int k = 0; k < 64; ++k) { float w = row[k]; a = fmaf(su[k], w, a); b = fmaf(sv[k], w, b); }
    At[j*4096 + o*64 + i] = a;
    Bt[j*4096 + o*64 + i] = b + e2b[q];
}

// per-block LDS histogram (no global hist atomics) + deg + classify
__global__ void k_eprep2(const int* __restrict__ ei, const float* __restrict__ ea,
                         const float* __restrict__ bp, const int* __restrict__ mc,
                         float* __restrict__ deg, int* __restrict__ pe, int* __restrict__ bh) {
    __shared__ int lh[65];
    int tid = threadIdx.x;
    if (tid < 65) lh[tid] = 0;
    __syncthreads();
    int e = blockIdx.x * 256 + tid;
    if (e < Ee) {
        atomicAdd(&deg[ei[Ee + e]], 1.0f);
        float a = ea[e];
        int m = *mc, p = 0;
        for (int j = 0; j < m; ++j) p += (bp[j] <= a) ? 1 : 0;
        pe[e] = p;
        atomicAdd(&lh[p], 1);
    }
    __syncthreads();
    if (tid < 65) bh[blockIdx.x*65 + tid] = lh[tid];
}

// blocks 0..58: dinv; block 59: two-level scan -> per-block per-bin cursors
__global__ void k_scan2(const float* __restrict__ deg, float* __restrict__ dinv,
                        const int* __restrict__ bh, int* __restrict__ bc) {
    int tid = threadIdx.x;
    if (blockIdx.x < 59) {
        int n = blockIdx.x * 256 + tid;
        if (n < Nn) dinv[n] = 1.0f / fmaxf(deg[n], 1.0f);
        return;
    }
    __shared__ int stot[65]; __shared__ int sbase[65];
    if (tid < 65) {
        int t = 0;
        for (int b = 0; b < NB_E; ++b) t += bh[b*65 + tid];
        stot[tid] = t;
    }
    __syncthreads();
    if (tid == 0) {
        int run = 0;
        for (int j = 0; j < 65; ++j) { sbase[j] = run; run += stot[j]; }
    }
    __syncthreads();
    if (tid < 65) {
        int run = sbase[tid];
        for (int b = 0; b < NB_E; ++b) { bc[b*65 + tid] = run; run += bh[b*65 + tid]; }
    }
}

// scatter using per-block LDS cursors (LDS atomics only)
__global__ void k_scatter2(const int* __restrict__ ei, const float* __restrict__ ea,
                           const int* __restrict__ pe, const int* __restrict__ bc,
                           int* __restrict__ sS, int* __restrict__ sD,
                           float* __restrict__ sA, int* __restrict__ sP) {
    __shared__ int cur[65];
    int tid = threadIdx.x;
    if (tid < 65) cur[tid] = bc[blockIdx.x*65 + tid];
    __syncthreads();
    int e = blockIdx.x * 256 + tid;
    if (e >= Ee) return;
    int p = pe[e];
    int pos = atomicAdd(&cur[p], 1);
    sS[pos] = ei[e]; sD[pos] = ei[Ee + e]; sA[pos] = ea[e]; sP[pos] = p;
}

// packed GRU weights for VGPR-resident matvecs:
// pk[g*4096 + i4*256 + lane*4 + k] = Wg[i4*4+k][lane]
// g: 0=root (rootw[i][o]); 1..3 = whh gates r,z,n; 4..6 = wih gates r,z,n
__global__ void k_wt2(const float* __restrict__ rootw, const float* __restrict__ whh,
                      const float* __restrict__ wih, float* __restrict__ pk) {
    int idx = blockIdx.x * 256 + threadIdx.x;
    if (idx >= 7*4096) return;
    int g = idx >> 12;
    int t = idx & 4095;
    int q4 = t >> 2, k = t & 3;
    int lane = q4 & 63;
    int i4 = q4 >> 6;
    int i = i4*4 + k;
    float v;
    if (g == 0)      v = rootw[i*64 + lane];
    else if (g < 4)  v = whh[((g-1)*64 + lane)*64 + i];
    else             v = wih[((g-4)*64 + lane)*64 + i];
    pk[idx] = v;
}

// pattern-sorted edges; wave's 8-edge chunk metadata loaded lane-parallel and
// broadcast via readlane; h-row load software-pipelined one edge ahead.
__global__ __launch_bounds__(256) void k_edge4(
        const int* __restrict__ sS, const int* __restrict__ sD,
        const float* __restrict__ sA, const int* __restrict__ sP,
        const float* __restrict__ out, const float* __restrict__ At,
        const float* __restrict__ Bt, const float* __restrict__ dinv,
        float* __restrict__ agg) {
    int tid = threadIdx.x, lane = tid & 63;
    int wid = (blockIdx.x * 256 + tid) >> 6;       // 0..EB*4-1
    const int CH = 8;
    int e0 = wid * CH;
    if (e0 >= Ee) return;
    int e1 = e0 + CH; if (e1 > Ee) e1 = Ee;
    int cnt = e1 - e0;

    // lane-parallel metadata for the whole chunk (lane l -> edge e0+l)
    int eidx = e0 + lane;
    int msrc = 0, mdst = 0, mp = 0; float ma = 0.f, mdv = 0.f;
    if (lane < cnt) {
        msrc = sS[eidx]; mdst = sD[eidx]; ma = sA[eidx]; mp = sP[eidx];
        mdv = dinv[mdst];
    }

    float Ar[64], Br[64];
    int curp = -1;
    float hv_next = out[bcasti(msrc, 0)*64 + lane];
    for (int j = 0; j < cnt; ++j) {
        float hv = hv_next;
        if (j+1 < cnt) hv_next = out[bcasti(msrc, j+1)*64 + lane];
        int p = bcasti(mp, j);
        if (p != curp) {
            curp = p;
            const float4* Ap4 = (const float4*)(At + p*4096 + lane*64);
            const float4* Bp4 = (const float4*)(Bt + p*4096 + lane*64);
            #pragma unroll
            for (int q = 0; q < 16; ++q) {
                float4 av = Ap4[q], bv = Bp4[q];
                Ar[q*4+0]=av.x; Ar[q*4+1]=av.y; Ar[q*4+2]=av.z; Ar[q*4+3]=av.w;
                Br[q*4+0]=bv.x; Br[q*4+1]=bv.y; Br[q*4+2]=bv.z; Br[q*4+3]=bv.w;
            }
        }
        float a = bcast(ma, j);
        float acc0 = 0.f, acc1 = 0.f;
        #pragma unroll
        for (int i = 0; i < 64; i += 2) {
            float h0 = bcast(hv, i);
            float h1 = bcast(hv, i+1);
            acc0 = fmaf(h0, fmaf(a, Ar[i],   Br[i]),   acc0);
            acc1 = fmaf(h1, fmaf(a, Ar[i+1], Br[i+1]), acc1);
        }
        float acc = (acc0 + acc1) * bcast(mdv, j);
        atomicAdd(&agg[bcasti(mdst, j)*64 + lane], acc);
    }
}

// fused NNConv-root + full GRU, k_edge-style: weights VGPR-resident per wave,
// operand broadcast via v_readlane from registers. 32-node tile, 8 waves:
// phase A = 4 gates{root,ghr,ghz,ghn} x 2 halves; phase B = 3 gi gates x 2 halves.
// Gates cross waves via 5 LDS buffers (40KB, stride-64 conflict-free).
__global__ __launch_bounds__(512, 4) void k_gru7(
        float* __restrict__ out, float* __restrict__ agg,
        const float* __restrict__ pk, const float* __restrict__ convb,
        const float* __restrict__ gbih, const float* __restrict__ gbhh) {
    __shared__ float mL[2048];   // m[ln][c]
    __shared__ float gA[2048];   // gh_r -> r
    __shared__ float gB[2048];   // gh_z -> z
    __shared__ float gC[2048];   // gh_n (raw)
    __shared__ float gD[2048];   // gi_n + bih_n
    int tid = threadIdx.x, lane = tid & 63;
    int w = tid >> 6;
    int n0 = blockIdx.x * 32;
    const float4* pk4 = (const float4*)pk;

    float4 wreg[16];
    int g = w >> 1, hf = w & 1;

    // ---- phase A: root, gh_r, gh_z, gh_n ----
    #pragma unroll
    for (int i4 = 0; i4 < 16; ++i4) wreg[i4] = pk4[(g*16 + i4)*64 + lane];

    int nb0 = n0 + hf*16;
    float cbv = convb[lane];
    for (int nb = 0; nb < 16; nb += 4) {
        int n = nb0 + nb;
        float hv0 = (n+0 < Nn) ? out[(n+0)*64 + lane] : 0.f;
        float hv1 = (n+1 < Nn) ? out[(n+1)*64 + lane] : 0.f;
        float hv2 = (n+2 < Nn) ? out[(n+2)*64 + lane] : 0.f;
        float hv3 = (n+3 < Nn) ? out[(n+3)*64 + lane] : 0.f;
        float a0 = 0.f, a1 = 0.f, a2 = 0.f, a3 = 0.f;
        #pragma unroll
        for (int i4 = 0; i4 < 16; ++i4) {
            float4 wv = wreg[i4];
            a0 = fmaf(bcast(hv0, i4*4+0), wv.x, a0);
            a1 = fmaf(bcast(hv1, i4*4+0), wv.x, a1);
            a2 = fmaf(bcast(hv2, i4*4+0), wv.x, a2);
            a3 = fmaf(bcast(hv3, i4*4+0), wv.x, a3);
            a0 = fmaf(bcast(hv0, i4*4+1), wv.y, a0);
            a1 = fmaf(bcast(hv1, i4*4+1), wv.y, a1);
            a2 = fmaf(bcast(hv2, i4*4+1), wv.y, a2);
            a3 = fmaf(bcast(hv3, i4*4+1), wv.y, a3);
            a0 = fmaf(bcast(hv0, i4*4+2), wv.z, a0);
            a1 = fmaf(bcast(hv1, i4*4+2), wv.z, a1);
            a2 = fmaf(bcast(hv2, i4*4+2), wv.z, a2);
            a3 = fmaf(bcast(hv3, i4*4+2), wv.z, a3);
            a0 = fmaf(bcast(hv0, i4*4+3), wv.w, a0);
            a1 = fmaf(bcast(hv1, i4*4+3), wv.w, a1);
            a2 = fmaf(bcast(hv2, i4*4+3), wv.w, a2);
            a3 = fmaf(bcast(hv3, i4*4+3), wv.w, a3);
        }
        int ln = n - n0;
        float ac[4] = {a0, a1, a2, a3};
        if (g == 0) {
            #pragma unroll
            for (int k2 = 0; k2 < 4; ++k2) {
                float mval = 0.f;
                if (n + k2 < Nn) {
                    float av = agg[(n+k2)*64 + lane];
                    agg[(n+k2)*64 + lane] = 0.f;
                    mval = fmaxf(ac[k2] + av + cbv, 0.f);
                }
                mL[(ln+k2)*64 + lane] = mval;
            }
        } else {
            float* gbuf = (g == 1) ? gA : (g == 2) ? gB : gC;
            #pragma unroll
            for (int k2 = 0; k2 < 4; ++k2) gbuf[(ln+k2)*64 + lane] = ac[k2];
        }
    }
    __syncthreads();

    // ---- phase B: gi_r, gi_z, gi_n (waves 0..5) ----
    if (w < 6) {
        int gb = w >> 1, hf2 = w & 1;
        #pragma unroll
        for (int i4 = 0; i4 < 16; ++i4) wreg[i4] = pk4[((4+gb)*16 + i4)*64 + lane];
        float bsum = (gb == 0) ? (gbih[lane] + gbhh[lane])
                   : (gb == 1) ? (gbih[64+lane] + gbhh[64+lane])
                   : gbih[128+lane];
        int lb0 = hf2*16;
        for (int nb = 0; nb < 16; nb += 4) {
            int ln = lb0 + nb;
            float mv0 = mL[(ln+0)*64 + lane];
            float mv1 = mL[(ln+1)*64 + lane];
            float mv2 = mL[(ln+2)*64 + lane];
            float mv3 = mL[(ln+3)*64 + lane];
            float a0 = 0.f, a1 = 0.f, a2 = 0.f, a3 = 0.f;
            #pragma unroll
            for (int i4 = 0; i4 < 16; ++i4) {
                float4 wv = wreg[i4];
                a0 = fmaf(bcast(mv0, i4*4+0), wv.x, a0);
                a1 = fmaf(bcast(mv1, i4*4+0), wv.x, a1);
                a2 = fmaf(bcast(mv2, i4*4+0), wv.x, a2);
                a3 = fmaf(bcast(mv3, i4*4+0), wv.x, a3);
                a0 = fmaf(bcast(mv0, i4*4+1), wv.y, a0);
                a1 = fmaf(bcast(mv1, i4*4+1), wv.y, a1);
                a2 = fmaf(bcast(mv2, i4*4+1), wv.y, a2);
                a3 = fmaf(bcast(mv3, i4*4+1), wv.y, a3);
                a0 = fmaf(bcast(mv0, i4*4+2), wv.z, a0);
                a1 = fmaf(bcast(mv1, i4*4+2), wv.z, a1);
                a2 = fmaf(bcast(mv2, i4*4+2), wv.z, a2);
                a3 = fmaf(bcast(mv3, i4*4+2), wv.z, a3);
                a0 = fmaf(bcast(mv0, i4*4+3), wv.w, a0);
                a1 = fmaf(bcast(mv1, i4*4+3), wv.w, a1);
                a2 = fmaf(bcast(mv2, i4*4+3), wv.w, a2);
                a3 = fmaf(bcast(mv3, i4*4+3), wv.w, a3);
            }
            float ac[4] = {a0, a1, a2, a3};
            if (gb == 0) {
                #pragma unroll
                for (int k2 = 0; k2 < 4; ++k2) {
                    int r = (ln+k2)*64 + lane;
                    gA[r] = sigf(ac[k2] + gA[r] + bsum);
                }
            } else if (gb == 1) {
                #pragma unroll
                for (int k2 = 0; k2 < 4; ++k2) {
                    int r = (ln+k2)*64 + lane;
                    gB[r] = sigf(ac[k2] + gB[r] + bsum);
                }
            } else {
                #pragma unroll
                for (int k2 = 0; k2 < 4; ++k2)
                    gD[(ln+k2)*64 + lane] = ac[k2] + bsum;
            }
        }
    }
    __syncthreads();

    // ---- combine ----
    float bhn = gbhh[128 + lane];
    #pragma unroll
    for (int p = 0; p < 4; ++p) {
        int site = p*512 + tid;          // 0..2047, c == lane
        int ln = site >> 6;
        int n = n0 + ln;
        if (n < Nn) {
            int r4 = ln*64 + lane;
            float r = gA[r4], z = gB[r4];
            float nn = tanhf(fmaf(r, gC[r4] + bhn, gD[r4]));
            float h = out[n*64 + lane];
            out[n*64 + lane] = (1.f - z)*nn + z*h;
        }
    }
}

// one launch per Set2Set iteration, 512 threads (2 waves/SIMD for latency hiding).
// Every block redundantly finalizes prev partials + runs the tiny LSTM, then
// computes its online-softmax partials. Double-buffered partials (rd/wr).
__global__ __launch_bounds__(512) void k_s2s(
        const float* __restrict__ wih, const float* __restrict__ whh,
        const float* __restrict__ bih, const float* __restrict__ bhh,
        float* __restrict__ hs, float* __restrict__ cs,
        const float* __restrict__ out,
        const float* __restrict__ gmax_rd, const float* __restrict__ gsum_rd,
        const float* __restrict__ gr_rd,
        float* __restrict__ gmax_wr, float* __restrict__ gsum_wr,
        float* __restrict__ gr_wr, int it) {
    __shared__ float red[512], shs[64], scs[64], srv[64], sg[256];
    __shared__ float sm_m[8], sm_z[8], sm_r[8][64];
    int tid = threadIdx.x, lane = tid & 63, w = tid >> 6;

    if (it == 0) {
        if (tid < 64) { shs[tid] = 0.f; scs[tid] = 0.f; srv[tid] = 0.f; }
    } else {
        float gm = (tid < 256) ? gmax_rd[tid] : -3.4e38f;
        red[tid] = gm; __syncthreads();
        for (int s = 256; s > 0; s >>= 1) { if (tid < s) red[tid] = fmaxf(red[tid], red[tid+s]); __syncthreads(); }
        float M = red[0]; __syncthreads();
        red[tid] = (tid < 256) ? gsum_rd[tid] * expf(gm - M) : 0.f; __syncthreads();
        for (int s = 256; s > 0; s >>= 1) { if (tid < s) red[tid] += red[tid+s]; __syncthreads(); }
        float Z = red[0]; __syncthreads();
        float racc = 0.f;
        for (int b = w; b < 256; b += 8) racc = fmaf(gr_rd[b*64 + lane], expf(gmax_rd[b] - M), racc);
        red[tid] = racc; __syncthreads();
        if (w == 0) {
            float s = 0.f;
            #pragma unroll
            for (int k = 0; k < 8; ++k) s += red[k*64 + lane];
            srv[lane] = s / Z;
        }
        if (tid < 64) { shs[tid] = hs[tid]; scs[tid] = cs[tid]; }
    }
    __syncthreads();

    // LSTM: g[tid] over 256 gates (waves 4-7 idle here)
    if (tid < 256) {
        const float* wi = wih + tid*128;
        const float* wh = whh + tid*64;
        float g = bih[tid] + bhh[tid];
        #pragma unroll 8
        for (int i = 0; i < 64; ++i) g += shs[i]*(wi[i] + wh[i]) + srv[i]*wi[64+i];
        sg[tid] = g;
    }
    __syncthreads();
    if (tid < 64) {
        float ii = sigf(sg[tid]), ff = sigf(sg[64+tid]);
        float gg = tanhf(sg[128+tid]), oo = sigf(sg[192+tid]);
        float c2 = ff*scs[tid] + ii*gg;
        float hn = oo*tanhf(c2);
        shs[tid] = hn;
        if (blockIdx.x == 0) { hs[tid] = hn; cs[tid] = c2; }
    }
    __syncthreads();

    // online-softmax partials with fresh hs
    float hsv = shs[lane];
    float m = -3.4e38f, Z2 = 0.f, racc2 = 0.f;
    for (int n = blockIdx.x*8 + w; n < Nn; n += 2048) {
        float ov = out[n*64 + lane];
        float p = ov * hsv;
        #pragma unroll
        for (int off = 32; off > 0; off >>= 1) p += __shfl_xor(p, off, 64);
        float mn = fmaxf(m, p);
        float sc = expf(m - mn);
        float t  = expf(p - mn);
        Z2 = fmaf(Z2, sc, t);
        racc2 = fmaf(racc2, sc, t*ov);
        m = mn;
    }
    if (lane == 0) { sm_m[w] = m; sm_z[w] = Z2; }
    sm_r[w][lane] = racc2;
    __syncthreads();
    if (w == 0) {
        float M = sm_m[0];
        #pragma unroll
        for (int j = 1; j < 8; ++j) M = fmaxf(M, sm_m[j]);
        float Zb = 0.f, rb = 0.f;
        #pragma unroll
        for (int j = 0; j < 8; ++j) {
            float e = expf(sm_m[j] - M);
            Zb = fmaf(sm_z[j], e, Zb);
            rb = fmaf(sm_r[j][lane], e, rb);
        }
        gr_wr[blockIdx.x*64 + lane] = rb;
        if (lane == 0) { gmax_wr[blockIdx.x] = M; gsum_wr[blockIdx.x] = Zb; }
    }
}

// final: finalize rv, mem-LSTM (h=c=0), lin1, lin3 -> dout = [v, hx(64), cx(64)]
__global__ __launch_bounds__(256) void k_final2(const float* __restrict__ mwih,
        const float* __restrict__ mbih, const float* __restrict__ mbhh,
        const float* __restrict__ hs,
        const float* __restrict__ gmax, const float* __restrict__ gsum,
        const float* __restrict__ gr,
        const float* __restrict__ l1w, const float* __restrict__ l1b,
        const float* __restrict__ l3w, const float* __restrict__ l3b,
        float* __restrict__ dout) {
    __shared__ float red[256], shs[64], srv[64], sg[256], shx[64], so[64];
    int tid = threadIdx.x, lane = tid & 63, w = tid >> 6;
    {
        float gm = gmax[tid];
        red[tid] = gm; __syncthreads();
        for (int s = 128; s > 0; s >>= 1) { if (tid < s) red[tid] = fmaxf(red[tid], red[tid+s]); __syncthreads(); }
        float M = red[0]; __syncthreads();
        red[tid] = gsum[tid] * expf(gm - M); __syncthreads();
        for (int s = 128; s > 0; s >>= 1) { if (tid < s) red[tid] += red[tid+s]; __syncthreads(); }
        float Z = red[0]; __syncthreads();
        float racc = 0.f;
        for (int b = w; b < 256; b += 4) racc = fmaf(gr[b*64 + lane], expf(gmax[b] - M), racc);
        red[tid] = racc; __syncthreads();
        if (w == 0) srv[lane] = (red[lane] + red[64+lane] + red[128+lane] + red[192+lane]) / Z;
        if (tid < 64) shs[tid] = hs[tid];
    }
    __syncthreads();
    const float* wi = mwih + tid*128;
    float g = mbih[tid] + mbhh[tid];
    #pragma unroll 8
    for (int i = 0; i < 64; ++i) g += shs[i]*wi[i] + srv[i]*wi[64+i];
    sg[tid] = g; __syncthreads();
    if (tid < 64) {
        float ii = sigf(sg[tid]);
        float gg = tanhf(sg[128+tid]);
        float oo = sigf(sg[192+tid]);
        float c2 = ii * gg;
        float hx = oo * tanhf(c2);
        shx[tid] = hx;
        dout[1 + tid] = hx;
        dout[65 + tid] = c2;
    }
    __syncthreads();
    if (tid < 64) {
        float a = l1b[tid];
        const float* wr = l1w + tid*64;
        #pragma unroll 8
        for (int i = 0; i < 64; ++i) a = fmaf(shx[i], wr[i], a);
        so[tid] = fmaxf(a, 0.f);
    }
    __syncthreads();
    if (tid == 0) {
        float v = l3b[0];
        for (int i = 0; i < 64; ++i) v = fmaf(so[i], l3w[i], v);
        dout[0] = v;
    }
}

extern "C" void kernel_launch(void* const* d_in, const int* in_sizes, int n_in,
                              void* d_out, int out_size, void* d_ws, size_t ws_size,
                              hipStream_t stream) {
    const float* x    = (const float*)d_in[0];
    const int*   ei   = (const int*)  d_in[1];
    const float* ea   = (const float*)d_in[2];
    const float* l0w  = (const float*)d_in[3];
    const float* l0b  = (const float*)d_in[4];
    const float* e1w  = (const float*)d_in[5];
    const float* e1b  = (const float*)d_in[6];
    const float* e2w  = (const float*)d_in[7];
    const float* e2b  = (const float*)d_in[8];
    const float* rootw= (const float*)d_in[9];
    const float* convb= (const float*)d_in[10];
    const float* gwih = (const float*)d_in[11];
    const float* gwhh = (const float*)d_in[12];
    const float* gbih = (const float*)d_in[13];
    const float* gbhh = (const float*)d_in[14];
    const float* swih = (const float*)d_in[15];
    const float* swhh = (const float*)d_in[16];
    const float* sbih = (const float*)d_in[17];
    const float* sbhh = (const float*)d_in[18];
    const float* mwih = (const float*)d_in[19];
    const float* mbih = (const float*)d_in[21];
    const float* mbhh = (const float*)d_in[22];
    const float* l1w  = (const float*)d_in[23];
    const float* l1b  = (const float*)d_in[24];
    const float* l3w  = (const float*)d_in[25];
    const float* l3b  = (const float*)d_in[26];

    float* ws   = (float*)d_ws;
    float* dout = (float*)d_out;
    if (ws_size < (size_t)WS_FLOATS * sizeof(float)) return;

    float* agg  = ws + OFF_AGG;
    float* deg  = ws + OFF_DEG;
    float* out  = ws + OFF_OUT;
    float* dinv = ws + OFF_DINV;
    float* At   = ws + OFF_AT;
    float* Bt   = ws + OFF_BT;
    float* bp   = ws + OFF_BP;
    float* ubuf = ws + OFF_U;
    float* vbuf = ws + OFF_V;
    int*   mc   = (int*)(ws + OFF_MC);
    int*   pe   = (int*)(ws + OFF_PE);
    int*   bh   = (int*)(ws + OFF_BH);
    int*   bc   = (int*)(ws + OFF_BC);
    int*   sS   = (int*)(ws + OFF_SS);
    int*   sD   = (int*)(ws + OFF_SD);
    float* sA   = ws + OFF_SA;
    int*   sP   = (int*)(ws + OFF_SP);
    float* pk   = ws + OFF_PK;
    float* gmA  = ws + OFF_GMA;
    float* gsA  = ws + OFF_GSA;
    float* grA  = ws + OFF_GRA;
    float* gmB  = ws + OFF_GMB;
    float* gsB  = ws + OFF_GSB;
    float* grB  = ws + OFF_GRB;
    float* hs   = ws + OFF_HS;
    float* cs   = ws + OFF_CS;

    hipMemsetAsync(d_ws, 0, (size_t)ZERO_END * sizeof(float), stream);

    k_lin0    <<<(Nn*64 + 255)/256, 256, 0, stream>>>(x, l0w, l0b, out);
    k_patterns<<<1, 64, 0, stream>>>(e1w, e1b, bp, ubuf, vbuf, mc);
    k_AB2     <<<65*16, 256, 0, stream>>>(e2w, e2b, ubuf, vbuf, mc, At, Bt);
    k_eprep2  <<<NB_E, 256, 0, stream>>>(ei, ea, bp, mc, deg, pe, bh);
    k_scan2   <<<60, 256, 0, stream>>>(deg, dinv, bh, bc);
    k_scatter2<<<NB_E, 256, 0, stream>>>(ei, ea, pe, bc, sS, sD, sA, sP);
    k_wt2     <<<(7*4096 + 255)/256, 256, 0, stream>>>(rootw, gwhh, gwih, pk);

    for (int s = 0; s < 6; ++s) {
        k_edge4<<<EB, 256, 0, stream>>>(sS, sD, sA, sP, out, At, Bt, dinv, agg);
        k_gru7 <<<(Nn + 31)/32, 512, 0, stream>>>(out, agg, pk, convb, gbih, gbhh);
    }

    for (int it = 0; it < 6; ++it) {
        float* gm_rd = (it & 1) ? gmA : gmB;   // unused at it=0
        float* gs_rd = (it & 1) ? gsA : gsB;
        float* gr_rd = (it & 1) ? grA : grB;
        float* gm_wr = (it & 1) ? gmB : gmA;
        float* gs_wr = (it & 1) ? gsB : gsA;
        float* gr_wr = (it & 1) ? grB : grA;
        k_s2s<<<256, 512, 0, stream>>>(swih, swhh, sbih, sbhh, hs, cs, out,
                                       gm_rd, gs_rd, gr_rd, gm_wr, gs_wr, gr_wr, it);
    }

    // it=5 wrote the B buffers
    k_final2<<<1, 256, 0, stream>>>(mwih, mbih, mbhh, hs, gmB, gsB, grB,
                                    l1w, l1b, l3w, l3b, dout);
}